// Round 8
// baseline (2766.052 us; speedup 1.0000x reference)
//
#include <hip/hip_runtime.h>

// LTC RNN (LiquidNeuralNetwork): B=512, S=512, H=128, 2 layers, RK4.
// Round 10 = round 9 (16 waves x 1 row-tile) with the REGISTER CAP FIXED.
// R9 failed because the compiler's occupancy heuristic (1024 thr + 35KB LDS ->
// 2 blocks/CU target) capped VGPR at 64; the wave needs ~110 (64 regs of
// weight frags + state) -> spill, WRITE_SIZE 3.8MB, dur 2720. launch_bounds'
// 2nd arg is only a MIN; amdgpu_waves_per_eu(4,4) pins 4 waves/SIMD =
// 1 block/CU -> VGPR cap 512, no spill. This properly tests the r9 theory:
// active-CU VALU pipe only 54% busy at 2-deep interleave (r8) -> 4-deep wave
// interleave + halved per-wave serial chain should push issue density up.
// Waves 0-7 = L0 tiles 0-7 @t; waves 8-15 = L1 tiles 0-7 @t-1 (lag-1).
// Kept: packed-f32 gate math, gx/bg folded into MFMA C-init, lgkm-only
// barriers, x-proj pipelined into slot B, f16 fragment pack, 4 slots/step.

typedef _Float16 f16;
typedef _Float16 f16x4 __attribute__((ext_vector_type(4)));
typedef _Float16 f16x8 __attribute__((ext_vector_type(8)));
typedef float f32x2 __attribute__((ext_vector_type(2)));
typedef float f32x4 __attribute__((ext_vector_type(4)));

#define NSTEP 512
#define OFF_A0 0
#define OFF_A1 32768
#define OFF_AIO 65536
#define OFF_AX 98304
#define W_TOTAL 122880

// LDS byte offsets. hh buffers: [16 cols][136 f16] = 4352 B each.
#define HQ0 0
#define HQ1 4352
#define L0A 8704
#define L0B 13056
#define L1A 17408
#define L1B 21760
#define L1H 26112
#define XT0 30464
#define XT1 32768
#define SMEM_BYTES 35072

__device__ __forceinline__ float rcp_f(float x) { return __builtin_amdgcn_rcpf(x); }

#define FMA2(A, B, C) __builtin_elementwise_fma((A), (B), (C))
#define B2(X) ((f32x2){(X), (X)})
#define ZERO4 ((f32x4){0.f, 0.f, 0.f, 0.f})
#define ZERO2 ((f32x2){0.f, 0.f})

// packed tanh: pk add + 2 scalar exp + pk add + 2 rcp + pk fma
__device__ __forceinline__ f32x2 tanh2_f(f32x2 z) {
  f32x2 zz = z + z;
  f32x2 e = {__expf(zz[0]), __expf(zz[1])};
  f32x2 d = e + 1.f;
  f32x2 r = {rcp_f(d[0]), rcp_f(d[1])};
  return FMA2(r, B2(-2.f), B2(1.f));
}
// packed sigmoid(t), t in [-1,1]: odd Taylor of 0.5+0.5*tanh(t/2), |err|<3e-6
__device__ __forceinline__ f32x2 sig2_f(f32x2 t) {
  f32x2 s = t * t;
  f32x2 p = FMA2(s, B2(2.1356861e-5f), B2(-2.1081349e-4f));
  p = FMA2(s, p, B2(2.0833333e-3f));
  p = FMA2(s, p, B2(-2.0833333e-2f));
  p = FMA2(s, p, B2(0.25f));
  return FMA2(t, p, B2(0.5f));
}

// lgkm-only barrier: LDS produce->consume needs lgkmcnt(0)+s_barrier only;
// does NOT drain vmcnt (seq prefetch stays in flight across barriers).
#define BAR()                                            \
  do {                                                   \
    asm volatile("s_waitcnt lgkmcnt(0)" ::: "memory");   \
    __builtin_amdgcn_s_barrier();                        \
  } while (0)

// Pack all recurrent-loop weights into f16 MFMA A-fragments.
// A-frag (16x16x32): A[m=lane&15][k=(lane>>4)*8+j], row-tile T = rows 16T..16T+15.
// A0 @0      [T8][sel2][kc4][lane64][j8]  sel0=Wg0 h-part, sel1=Wrec0
// A1 @32768  same                          sel0=Wg1 h-part, sel1=Wrec1
// AIO@65536  same                          sel0=Win1,       sel1=Wg1 x-part
// AX @98304  [T8][sel2][kc3][lane64][j8]  sel0=Win0,       sel1=Wg0 x-part (K=96)
__global__ __launch_bounds__(256) void prep_kernel(
    const float* __restrict__ Win0, const float* __restrict__ Wrec0,
    const float* __restrict__ Wg0, const float* __restrict__ Win1,
    const float* __restrict__ Wrec1, const float* __restrict__ Wg1,
    f16* __restrict__ W) {
  int i = blockIdx.x * 256 + threadIdx.x;
  if (i >= W_TOTAL) return;
  if (i < OFF_AX) {
    int sec = i >> 15;
    int r = i & 32767;
    int j = r & 7, lane = (r >> 3) & 63, kc = (r >> 9) & 3, sel = (r >> 11) & 1,
        w = (r >> 12) & 7;
    int row = w * 16 + (lane & 15);
    int k = kc * 32 + ((lane >> 4) << 3) + j;
    float v;
    if (sec == 0)
      v = sel ? Wrec0[row * 128 + k] : Wg0[row * 224 + 96 + k];
    else if (sec == 1)
      v = sel ? Wrec1[row * 128 + k] : Wg1[row * 256 + 128 + k];
    else
      v = sel ? Wg1[row * 256 + k] : Win1[row * 128 + k];
    W[i] = (f16)v;
  } else {
    int r = i - OFF_AX;
    int j = r & 7, lane = (r >> 3) & 63, g = r >> 9;
    int kc = g % 3, sg = g / 3;
    int sel = sg & 1, w = sg >> 1;
    int row = w * 16 + (lane & 15);
    int k = kc * 32 + ((lane >> 4) << 3) + j;
    W[i] = (f16)(sel ? Wg0[row * 224 + k] : Win0[row * 96 + k]);
  }
}

#define MFMA16(A, B, C) __builtin_amdgcn_mfma_f32_16x16x32_f16((A), (B), (C), 0, 0, 0)

// recurrent matvec (1 tile), gx folded: ga = gx4 + Wg_h*h; ra = Wrec*h
#define MM2G(SRC)                                                   \
  {                                                                 \
    ga = gx4; ra = ZERO4;                                           \
    const f16* bp_ = (SRC) + c * 136 + 8 * q;                       \
    _Pragma("unroll") for (int kc_ = 0; kc_ < 4; ++kc_) {           \
      f16x8 bf_ = *(const f16x8*)(bp_ + kc_ * 32);                  \
      ga = MFMA16(awg[kc_], bf_, ga);                               \
      ra = MFMA16(awr[kc_], bf_, ra);                               \
    }                                                               \
  }

// L1 io projection (1 tile), bg folded: ga = Win1*h0; ra = bg + Wg1x*h0
#define MMIO_B(SRC)                                                 \
  {                                                                 \
    ga = ZERO4; ra = bgv4;                                          \
    const f16* bp_ = (SRC) + c * 136 + 8 * q;                       \
    _Pragma("unroll") for (int kc_ = 0; kc_ < 4; ++kc_) {           \
      f16x8 bf_ = *(const f16x8*)(bp_ + kc_ * 32);                  \
      ga = MFMA16(au[kc_], bf_, ga);                                \
      ra = MFMA16(ag2[kc_], bf_, ra);                               \
    }                                                               \
  }

// L0 x-projection (1 tile, K=96: 2 chunks from x-tile + ctx), bg folded:
// UD = Win0*x; GD = bg + Wg0x*x
#define XPROJ(XSRC, UD, GD)                                         \
  {                                                                 \
    f32x4 tg_ = ZERO4, tr_ = bgv4;                                  \
    f16x8 bx0_ = *(const f16x8*)((XSRC) + c * 72 + 8 * q);          \
    f16x8 bx1_ = *(const f16x8*)((XSRC) + c * 72 + 32 + 8 * q);     \
    tg_ = MFMA16(au[0], bx0_, tg_); tr_ = MFMA16(ag2[0], bx0_, tr_);\
    tg_ = MFMA16(au[1], bx1_, tg_); tr_ = MFMA16(ag2[1], bx1_, tr_);\
    tg_ = MFMA16(au[2], bctx, tg_); tr_ = MFMA16(ag2[2], bctx, tr_);\
    (UD) = tg_; (GD) = tr_;                                         \
  }

// RK stage body (1 tile), packed pairs. Gate arg complete in ga (gx folded).
// FIRST=1: ksum = kk (stage 1). Else ksum += WC*kk.
#define GATEP(WC, HC, DST, FIRST)                                   \
  {                                                                 \
    f16x4 hv_;                                                      \
    _Pragma("unroll") for (int p_ = 0; p_ < 2; ++p_) {              \
      f32x2 z_ = {ga[2 * p_], ga[2 * p_ + 1]};                      \
      f32x2 rr_ = {ra[2 * p_], ra[2 * p_ + 1]};                     \
      f32x2 th_ = tanh2_f(z_);                                      \
      f32x2 gt_ = sig2_f(th_);                                      \
      f32x2 kk_ = FMA2(gt_, rr_, FMA2(nitv2[p_], hhc2[p_], u2[p_])); \
      ksum2[p_] = (FIRST) ? kk_ : FMA2(B2(WC), kk_, ksum2[p_]);     \
      f32x2 hn_ = FMA2(B2(HC), kk_, hst2[p_]);                      \
      hhc2[p_] = hn_;                                               \
      hv_[2 * p_] = (f16)hn_[0];                                    \
      hv_[2 * p_ + 1] = (f16)hn_[1];                                \
    }                                                               \
    *(f16x4*)((DST) + c * 136 + jbase) = hv_;                       \
  }

// RK stage 4: h_new = tanh(h + (ksum+kk)/6) -> state + next stage-1 eval.
#define GATEF(DST)                                                  \
  {                                                                 \
    f16x4 hv_;                                                      \
    _Pragma("unroll") for (int p_ = 0; p_ < 2; ++p_) {              \
      f32x2 z_ = {ga[2 * p_], ga[2 * p_ + 1]};                      \
      f32x2 rr_ = {ra[2 * p_], ra[2 * p_ + 1]};                     \
      f32x2 th_ = tanh2_f(z_);                                      \
      f32x2 gt_ = sig2_f(th_);                                      \
      f32x2 kk_ = FMA2(gt_, rr_, FMA2(nitv2[p_], hhc2[p_], u2[p_])); \
      f32x2 ks_ = ksum2[p_] + kk_;                                  \
      f32x2 hn_ = tanh2_f(FMA2(B2(0.16666667f), ks_, hst2[p_]));    \
      hst2[p_] = hn_;                                               \
      hhc2[p_] = hn_;                                               \
      hv_[2 * p_] = (f16)hn_[0];                                    \
      hv_[2 * p_ + 1] = (f16)hn_[1];                                \
    }                                                               \
    *(f16x4*)((DST) + c * 136 + jbase) = hv_;                       \
  }

__global__ __launch_bounds__(1024, 4) __attribute__((amdgpu_waves_per_eu(4, 4)))
void ltc_kernel(
    const float* __restrict__ seq, const float* __restrict__ ctx,
    const float* __restrict__ tau0p, const float* __restrict__ bg0p,
    const float* __restrict__ tau1p, const float* __restrict__ bg1p,
    const float* __restrict__ W1, const float* __restrict__ b1,
    const float* __restrict__ W2, const float* __restrict__ b2,
    const f16* __restrict__ W, float* __restrict__ out) {
  __shared__ __align__(16) char smem[SMEM_BYTES];
  f16* hq0 = (f16*)(smem + HQ0);
  f16* hq1 = (f16*)(smem + HQ1);
  f16* l0a = (f16*)(smem + L0A);
  f16* l0b = (f16*)(smem + L0B);
  f16* l1a = (f16*)(smem + L1A);
  f16* l1b = (f16*)(smem + L1B);
  f16* l1h = (f16*)(smem + L1H);
  f16* xt0 = (f16*)(smem + XT0);
  f16* xt1 = (f16*)(smem + XT1);

  const int tid = threadIdx.x;
  const int w16 = tid >> 6, lane = tid & 63;
  const int q = lane >> 4, c = lane & 15;
  const int wl = w16 & 7;  // row-tile T (0..7)
  const bool isL0 = (w16 < 8);
  const int bg = blockIdx.x;
  const int jbase = 16 * wl + 4 * q;  // this wave's tile, lane's 4 rows

  f16* bufA = isL0 ? l0a : l1a;
  f16* bufB = isL0 ? l0b : l1b;

  // ---- weight fragments -> VGPRs (held for whole kernel), 1 tile/wave ----
  f16x8 awg[4], awr[4], au[4], ag2[4];
  f16x8 bctx = (f16x8)(f16)0.f;
  if (isL0) {
#pragma unroll
    for (int kc = 0; kc < 4; ++kc) {
      awg[kc] = *(const f16x8*)(W + OFF_A0 + (((wl * 2 + 0) * 4 + kc) * 64 + lane) * 8);
      awr[kc] = *(const f16x8*)(W + OFF_A0 + (((wl * 2 + 1) * 4 + kc) * 64 + lane) * 8);
    }
#pragma unroll
    for (int kc = 0; kc < 3; ++kc) {
      au[kc] = *(const f16x8*)(W + OFF_AX + (((wl * 2 + 0) * 3 + kc) * 64 + lane) * 8);
      ag2[kc] = *(const f16x8*)(W + OFF_AX + (((wl * 2 + 1) * 3 + kc) * 64 + lane) * 8);
    }
    au[3] = (f16x8)(f16)0.f;
    ag2[3] = (f16x8)(f16)0.f;
    const float* cp = ctx + (bg * 16 + c) * 32 + 8 * q;
#pragma unroll
    for (int j = 0; j < 8; ++j) bctx[j] = (f16)cp[j];
  } else {
#pragma unroll
    for (int kc = 0; kc < 4; ++kc) {
      awg[kc] = *(const f16x8*)(W + OFF_A1 + (((wl * 2 + 0) * 4 + kc) * 64 + lane) * 8);
      awr[kc] = *(const f16x8*)(W + OFF_A1 + (((wl * 2 + 1) * 4 + kc) * 64 + lane) * 8);
      au[kc] = *(const f16x8*)(W + OFF_AIO + (((wl * 2 + 0) * 4 + kc) * 64 + lane) * 8);
      ag2[kc] = *(const f16x8*)(W + OFF_AIO + (((wl * 2 + 1) * 4 + kc) * 64 + lane) * 8);
    }
  }

  // per-lane params for the 4 owned rows (packed pairs, itv negated)
  const float* taup = isL0 ? tau0p : tau1p;
  const float* bgp = isL0 ? bg0p : bg1p;
  f32x2 nitv2[2];
  f32x4 bgv4;
#pragma unroll
  for (int r = 0; r < 4; ++r) {
    float t = taup[jbase + r];
    nitv2[r >> 1][r & 1] = -1.f / (logf(1.f + __expf(t)) + 1.f);
    bgv4[r] = bgp[jbase + r];
  }

  f32x2 hst2[2], hhc2[2], ksum2[2], u2[2];
  f32x4 ga, ra, gx4, un4, gxn4;
#pragma unroll
  for (int p = 0; p < 2; ++p) {
    hst2[p] = ZERO2;
    hhc2[p] = ZERO2;
    ksum2[p] = ZERO2;
    u2[p] = ZERO2;
  }
  gx4 = ZERO4;
  un4 = ZERO4;
  gxn4 = ZERO4;

  // zero initial-state buffers: hq1 (h0 at t=-1) and l1h (h1 at t=-1)
  for (int j = tid; j < 2176; j += 1024) {
    hq1[j] = (f16)0.f;
    l1h[j] = (f16)0.f;
  }
  // pre-stage x(0): 256 threads (all in L0 waves 0-3), float4 each
  const int bs = tid >> 4, fp = tid & 15;
  const size_t seqrow = ((size_t)(bg * 16 + bs)) * NSTEP * 64 + 4 * fp;
  float4 sq_nxt = {0.f, 0.f, 0.f, 0.f};
  float4 sq_ld = sq_nxt;
  if (tid < 256) {
    float4 sv = *(const float4*)(seq + seqrow);
    *(f16x4*)(xt0 + bs * 72 + 4 * fp) =
        (f16x4){(f16)sv.x, (f16)sv.y, (f16)sv.z, (f16)sv.w};
    sq_nxt = *(const float4*)(seq + seqrow + 64);  // x(1)
  }
  __syncthreads();
  // u/gx for step 0 (pipeline warm-up)
  if (isL0) {
    XPROJ(xt0, un4, gxn4);
    u2[0] = (f32x2){un4[0], un4[1]};
    u2[1] = (f32x2){un4[2], un4[3]};
    gx4 = gxn4;
  }

#pragma unroll 1
  for (int i = 0; i <= NSTEP; ++i) {
    const f16* hprev = ((i + 1) & 1) ? hq1 : hq0;  // h0(t-1) buffer
    f16* xw = ((i + 1) & 1) ? xt1 : xt0;           // buffer for x(i+1)

    // ===== slot A: L0 stage1 (+stage x(i+1), issue x(i+2)) | L1 io + stage1
    if (isL0) {
      if (i < NSTEP) {
        if (tid < 256 && i + 2 < NSTEP)
          sq_ld = *(const float4*)(seq + seqrow + (size_t)(i + 2) * 64);
        MM2G(hprev);  // stage 1 on h0(t-1) -- the critical prefix
        if (tid < 256 && i + 1 < NSTEP)
          *(f16x4*)(xw + bs * 72 + 4 * fp) =
              (f16x4){(f16)sq_nxt.x, (f16)sq_nxt.y, (f16)sq_nxt.z, (f16)sq_nxt.w};
        GATEP(1.0f, 0.5f, bufA, 1);
      }
    } else {
      if (i >= 1) {
        MMIO_B(hprev);  // u1 = Win1*h0_new, g1x = bg + Wg1x*h0_new
        u2[0] = (f32x2){ga[0], ga[1]};
        u2[1] = (f32x2){ga[2], ga[3]};
        gx4 = ra;
        MM2G(l1h);  // stage 1 on h1(t-2)
        GATEP(1.0f, 0.5f, bufA, 1);
      }
    }
    BAR();

    // ===== slot B: stage 2 ; L0 also computes x-proj(i+1) off-path =====
    if (isL0) {
      if (i < NSTEP) {
        MM2G(bufA);
        GATEP(2.0f, 0.5f, bufB, 0);
        if (i + 1 < NSTEP) { XPROJ(xw, un4, gxn4); }
      }
    } else if (i >= 1) {
      MM2G(bufA);
      GATEP(2.0f, 0.5f, bufB, 0);
    }
    BAR();

    // ===== slot C: stage 3 =====
    if ((isL0 && i < NSTEP) || (!isL0 && i >= 1)) {
      MM2G(bufB);
      GATEP(2.0f, 1.0f, bufA, 0);
    }
    BAR();

    // ===== slot D: stage 4 -> h_new; L0 commits pipelined u/gx + seq reg =====
    if (isL0) {
      if (i < NSTEP) {
        MM2G(bufA);
        GATEF((i & 1) ? hq1 : hq0);
        if (i + 1 < NSTEP) {
          u2[0] = (f32x2){un4[0], un4[1]};
          u2[1] = (f32x2){un4[2], un4[3]};
          gx4 = gxn4;
          if (i + 2 < NSTEP) sq_nxt = sq_ld;
        }
      }
    } else if (i >= 1) {
      MM2G(bufA);
      GATEF(l1h);
    }
    BAR();
  }

  // ======================= classifier epilogue ===========================
  float* h1f = (float*)smem;  // [16][132] f32
  if (!isL0) {
#pragma unroll
    for (int p = 0; p < 2; ++p)
      *(f32x2*)(h1f + c * 132 + jbase + 2 * p) = hst2[p];
  }
  __syncthreads();
  float* z1 = (float*)(smem + 16 * 132 * 4);  // [16][64] f32
  {
    int b = tid >> 5, o = tid & 31;
    if (b < 16) {
#pragma unroll
      for (int hlf = 0; hlf < 2; ++hlf) {
        int oo = o + 32 * hlf;
        const float* wr = W1 + oo * 128;
        const float* hr = h1f + b * 132;
        float s = 0.f;
#pragma unroll
        for (int j = 0; j < 128; j += 4) {
          f32x4 wv = *(const f32x4*)(wr + j);
          f32x4 hv = *(const f32x4*)(hr + j);
          s += wv[0] * hv[0] + wv[1] * hv[1] + wv[2] * hv[2] + wv[3] * hv[3];
        }
        s += b1[oo];
        z1[b * 64 + oo] = fmaxf(s, 0.f);
      }
    }
  }
  __syncthreads();
  if (tid < 16) {
    float s = b2[0];
#pragma unroll
    for (int o = 0; o < 64; ++o) s += z1[tid * 64 + o] * W2[o];
    out[bg * 16 + tid] = rcp_f(1.f + __expf(-s));
  }
}

extern "C" void kernel_launch(void* const* d_in, const int* in_sizes, int n_in,
                              void* d_out, int out_size, void* d_ws, size_t ws_size,
                              hipStream_t stream) {
  (void)in_sizes; (void)n_in; (void)out_size; (void)ws_size;
  const float* seq = (const float*)d_in[0];
  const float* ctx = (const float*)d_in[1];
  const float* tau0 = (const float*)d_in[2];
  const float* Win0 = (const float*)d_in[3];
  const float* Wrec0 = (const float*)d_in[4];
  const float* Wg0 = (const float*)d_in[5];
  const float* bg0 = (const float*)d_in[6];
  const float* tau1 = (const float*)d_in[7];
  const float* Win1 = (const float*)d_in[8];
  const float* Wrec1 = (const float*)d_in[9];
  const float* Wg1 = (const float*)d_in[10];
  const float* bg1 = (const float*)d_in[11];
  const float* W1 = (const float*)d_in[12];
  const float* b1 = (const float*)d_in[13];
  const float* W2 = (const float*)d_in[14];
  const float* b2 = (const float*)d_in[15];
  f16* W = (f16*)d_ws;  // 245760 B of packed fragments

  prep_kernel<<<480, 256, 0, stream>>>(Win0, Wrec0, Wg0, Win1, Wrec1, Wg1, W);
  ltc_kernel<<<32, 1024, 0, stream>>>(seq, ctx, tau0, bg0, tau1, bg1, W1, b1,
                                      W2, b2, W, (float*)d_out);
}

// Round 9
// 2759.924 us; speedup vs baseline: 1.0022x; 1.0022x over previous
//
#include <hip/hip_runtime.h>

// LTC RNN (LiquidNeuralNetwork): B=512, S=512, H=128, 2 layers, RK4.
// Round 11 = round 9/10 (16 waves x 1 row-tile) with the waves-per-eu attribute
// made EFFECTIVE. r10's __launch_bounds__(1024,4) itself lowers to
// amdgpu-waves-per-eu={4,} and the duplicate explicit attribute was dropped ->
// compiler still targeted 8 waves/EU, chose VGPR=64, spilled ~29 regs/thread
// (WRITE_SIZE 3.8MB one-time; per-step reloads hit L2-cached scratch -> ~200cy
// on every MM2G critical path; invisible in FETCH which is HBM-only).
// Fix: single-arg __launch_bounds__(1024) (flat-work-group-size only) +
// __attribute__((amdgpu_waves_per_eu(4,4))) as the sole waves-per-eu source:
// min=max=4 waves/EU = 1 block/CU -> VGPR budget 512/wave, weights stay
// resident. This cleanly tests the 4-deep TLP theory (r8: active-CU VALU only
// 54% busy at 2-deep interleave).
// Waves 0-7 = L0 tiles 0-7 @t; waves 8-15 = L1 tiles 0-7 @t-1 (lag-1).
// Kept: packed-f32 gate math, gx/bg folded into MFMA C-init, lgkm-only
// barriers, x-proj pipelined into slot B, f16 fragment pack, 4 slots/step.

typedef _Float16 f16;
typedef _Float16 f16x4 __attribute__((ext_vector_type(4)));
typedef _Float16 f16x8 __attribute__((ext_vector_type(8)));
typedef float f32x2 __attribute__((ext_vector_type(2)));
typedef float f32x4 __attribute__((ext_vector_type(4)));

#define NSTEP 512
#define OFF_A0 0
#define OFF_A1 32768
#define OFF_AIO 65536
#define OFF_AX 98304
#define W_TOTAL 122880

// LDS byte offsets. hh buffers: [16 cols][136 f16] = 4352 B each.
#define HQ0 0
#define HQ1 4352
#define L0A 8704
#define L0B 13056
#define L1A 17408
#define L1B 21760
#define L1H 26112
#define XT0 30464
#define XT1 32768
#define SMEM_BYTES 35072

__device__ __forceinline__ float rcp_f(float x) { return __builtin_amdgcn_rcpf(x); }

#define FMA2(A, B, C) __builtin_elementwise_fma((A), (B), (C))
#define B2(X) ((f32x2){(X), (X)})
#define ZERO4 ((f32x4){0.f, 0.f, 0.f, 0.f})
#define ZERO2 ((f32x2){0.f, 0.f})

// packed tanh: pk add + 2 scalar exp + pk add + 2 rcp + pk fma
__device__ __forceinline__ f32x2 tanh2_f(f32x2 z) {
  f32x2 zz = z + z;
  f32x2 e = {__expf(zz[0]), __expf(zz[1])};
  f32x2 d = e + 1.f;
  f32x2 r = {rcp_f(d[0]), rcp_f(d[1])};
  return FMA2(r, B2(-2.f), B2(1.f));
}
// packed sigmoid(t), t in [-1,1]: odd Taylor of 0.5+0.5*tanh(t/2), |err|<3e-6
__device__ __forceinline__ f32x2 sig2_f(f32x2 t) {
  f32x2 s = t * t;
  f32x2 p = FMA2(s, B2(2.1356861e-5f), B2(-2.1081349e-4f));
  p = FMA2(s, p, B2(2.0833333e-3f));
  p = FMA2(s, p, B2(-2.0833333e-2f));
  p = FMA2(s, p, B2(0.25f));
  return FMA2(t, p, B2(0.5f));
}

// lgkm-only barrier: LDS produce->consume needs lgkmcnt(0)+s_barrier only;
// does NOT drain vmcnt (seq prefetch stays in flight across barriers).
#define BAR()                                            \
  do {                                                   \
    asm volatile("s_waitcnt lgkmcnt(0)" ::: "memory");   \
    __builtin_amdgcn_s_barrier();                        \
  } while (0)

// Pack all recurrent-loop weights into f16 MFMA A-fragments.
// A-frag (16x16x32): A[m=lane&15][k=(lane>>4)*8+j], row-tile T = rows 16T..16T+15.
// A0 @0      [T8][sel2][kc4][lane64][j8]  sel0=Wg0 h-part, sel1=Wrec0
// A1 @32768  same                          sel0=Wg1 h-part, sel1=Wrec1
// AIO@65536  same                          sel0=Win1,       sel1=Wg1 x-part
// AX @98304  [T8][sel2][kc3][lane64][j8]  sel0=Win0,       sel1=Wg0 x-part (K=96)
__global__ __launch_bounds__(256) void prep_kernel(
    const float* __restrict__ Win0, const float* __restrict__ Wrec0,
    const float* __restrict__ Wg0, const float* __restrict__ Win1,
    const float* __restrict__ Wrec1, const float* __restrict__ Wg1,
    f16* __restrict__ W) {
  int i = blockIdx.x * 256 + threadIdx.x;
  if (i >= W_TOTAL) return;
  if (i < OFF_AX) {
    int sec = i >> 15;
    int r = i & 32767;
    int j = r & 7, lane = (r >> 3) & 63, kc = (r >> 9) & 3, sel = (r >> 11) & 1,
        w = (r >> 12) & 7;
    int row = w * 16 + (lane & 15);
    int k = kc * 32 + ((lane >> 4) << 3) + j;
    float v;
    if (sec == 0)
      v = sel ? Wrec0[row * 128 + k] : Wg0[row * 224 + 96 + k];
    else if (sec == 1)
      v = sel ? Wrec1[row * 128 + k] : Wg1[row * 256 + 128 + k];
    else
      v = sel ? Wg1[row * 256 + k] : Win1[row * 128 + k];
    W[i] = (f16)v;
  } else {
    int r = i - OFF_AX;
    int j = r & 7, lane = (r >> 3) & 63, g = r >> 9;
    int kc = g % 3, sg = g / 3;
    int sel = sg & 1, w = sg >> 1;
    int row = w * 16 + (lane & 15);
    int k = kc * 32 + ((lane >> 4) << 3) + j;
    W[i] = (f16)(sel ? Wg0[row * 224 + k] : Win0[row * 96 + k]);
  }
}

#define MFMA16(A, B, C) __builtin_amdgcn_mfma_f32_16x16x32_f16((A), (B), (C), 0, 0, 0)

// recurrent matvec (1 tile), gx folded: ga = gx4 + Wg_h*h; ra = Wrec*h
#define MM2G(SRC)                                                   \
  {                                                                 \
    ga = gx4; ra = ZERO4;                                           \
    const f16* bp_ = (SRC) + c * 136 + 8 * q;                       \
    _Pragma("unroll") for (int kc_ = 0; kc_ < 4; ++kc_) {           \
      f16x8 bf_ = *(const f16x8*)(bp_ + kc_ * 32);                  \
      ga = MFMA16(awg[kc_], bf_, ga);                               \
      ra = MFMA16(awr[kc_], bf_, ra);                               \
    }                                                               \
  }

// L1 io projection (1 tile), bg folded: ga = Win1*h0; ra = bg + Wg1x*h0
#define MMIO_B(SRC)                                                 \
  {                                                                 \
    ga = ZERO4; ra = bgv4;                                          \
    const f16* bp_ = (SRC) + c * 136 + 8 * q;                       \
    _Pragma("unroll") for (int kc_ = 0; kc_ < 4; ++kc_) {           \
      f16x8 bf_ = *(const f16x8*)(bp_ + kc_ * 32);                  \
      ga = MFMA16(au[kc_], bf_, ga);                                \
      ra = MFMA16(ag2[kc_], bf_, ra);                               \
    }                                                               \
  }

// L0 x-projection (1 tile, K=96: 2 chunks from x-tile + ctx), bg folded:
// UD = Win0*x; GD = bg + Wg0x*x
#define XPROJ(XSRC, UD, GD)                                         \
  {                                                                 \
    f32x4 tg_ = ZERO4, tr_ = bgv4;                                  \
    f16x8 bx0_ = *(const f16x8*)((XSRC) + c * 72 + 8 * q);          \
    f16x8 bx1_ = *(const f16x8*)((XSRC) + c * 72 + 32 + 8 * q);     \
    tg_ = MFMA16(au[0], bx0_, tg_); tr_ = MFMA16(ag2[0], bx0_, tr_);\
    tg_ = MFMA16(au[1], bx1_, tg_); tr_ = MFMA16(ag2[1], bx1_, tr_);\
    tg_ = MFMA16(au[2], bctx, tg_); tr_ = MFMA16(ag2[2], bctx, tr_);\
    (UD) = tg_; (GD) = tr_;                                         \
  }

// RK stage body (1 tile), packed pairs. Gate arg complete in ga (gx folded).
// FIRST=1: ksum = kk (stage 1). Else ksum += WC*kk.
#define GATEP(WC, HC, DST, FIRST)                                   \
  {                                                                 \
    f16x4 hv_;                                                      \
    _Pragma("unroll") for (int p_ = 0; p_ < 2; ++p_) {              \
      f32x2 z_ = {ga[2 * p_], ga[2 * p_ + 1]};                      \
      f32x2 rr_ = {ra[2 * p_], ra[2 * p_ + 1]};                     \
      f32x2 th_ = tanh2_f(z_);                                      \
      f32x2 gt_ = sig2_f(th_);                                      \
      f32x2 kk_ = FMA2(gt_, rr_, FMA2(nitv2[p_], hhc2[p_], u2[p_])); \
      ksum2[p_] = (FIRST) ? kk_ : FMA2(B2(WC), kk_, ksum2[p_]);     \
      f32x2 hn_ = FMA2(B2(HC), kk_, hst2[p_]);                      \
      hhc2[p_] = hn_;                                               \
      hv_[2 * p_] = (f16)hn_[0];                                    \
      hv_[2 * p_ + 1] = (f16)hn_[1];                                \
    }                                                               \
    *(f16x4*)((DST) + c * 136 + jbase) = hv_;                       \
  }

// RK stage 4: h_new = tanh(h + (ksum+kk)/6) -> state + next stage-1 eval.
#define GATEF(DST)                                                  \
  {                                                                 \
    f16x4 hv_;                                                      \
    _Pragma("unroll") for (int p_ = 0; p_ < 2; ++p_) {              \
      f32x2 z_ = {ga[2 * p_], ga[2 * p_ + 1]};                      \
      f32x2 rr_ = {ra[2 * p_], ra[2 * p_ + 1]};                     \
      f32x2 th_ = tanh2_f(z_);                                      \
      f32x2 gt_ = sig2_f(th_);                                      \
      f32x2 kk_ = FMA2(gt_, rr_, FMA2(nitv2[p_], hhc2[p_], u2[p_])); \
      f32x2 ks_ = ksum2[p_] + kk_;                                  \
      f32x2 hn_ = tanh2_f(FMA2(B2(0.16666667f), ks_, hst2[p_]));    \
      hst2[p_] = hn_;                                               \
      hhc2[p_] = hn_;                                               \
      hv_[2 * p_] = (f16)hn_[0];                                    \
      hv_[2 * p_ + 1] = (f16)hn_[1];                                \
    }                                                               \
    *(f16x4*)((DST) + c * 136 + jbase) = hv_;                       \
  }

__global__ __launch_bounds__(1024) __attribute__((amdgpu_waves_per_eu(4, 4)))
void ltc_kernel(
    const float* __restrict__ seq, const float* __restrict__ ctx,
    const float* __restrict__ tau0p, const float* __restrict__ bg0p,
    const float* __restrict__ tau1p, const float* __restrict__ bg1p,
    const float* __restrict__ W1, const float* __restrict__ b1,
    const float* __restrict__ W2, const float* __restrict__ b2,
    const f16* __restrict__ W, float* __restrict__ out) {
  __shared__ __align__(16) char smem[SMEM_BYTES];
  f16* hq0 = (f16*)(smem + HQ0);
  f16* hq1 = (f16*)(smem + HQ1);
  f16* l0a = (f16*)(smem + L0A);
  f16* l0b = (f16*)(smem + L0B);
  f16* l1a = (f16*)(smem + L1A);
  f16* l1b = (f16*)(smem + L1B);
  f16* l1h = (f16*)(smem + L1H);
  f16* xt0 = (f16*)(smem + XT0);
  f16* xt1 = (f16*)(smem + XT1);

  const int tid = threadIdx.x;
  const int w16 = tid >> 6, lane = tid & 63;
  const int q = lane >> 4, c = lane & 15;
  const int wl = w16 & 7;  // row-tile T (0..7)
  const bool isL0 = (w16 < 8);
  const int bg = blockIdx.x;
  const int jbase = 16 * wl + 4 * q;  // this wave's tile, lane's 4 rows

  f16* bufA = isL0 ? l0a : l1a;
  f16* bufB = isL0 ? l0b : l1b;

  // ---- weight fragments -> VGPRs (held for whole kernel), 1 tile/wave ----
  f16x8 awg[4], awr[4], au[4], ag2[4];
  f16x8 bctx = (f16x8)(f16)0.f;
  if (isL0) {
#pragma unroll
    for (int kc = 0; kc < 4; ++kc) {
      awg[kc] = *(const f16x8*)(W + OFF_A0 + (((wl * 2 + 0) * 4 + kc) * 64 + lane) * 8);
      awr[kc] = *(const f16x8*)(W + OFF_A0 + (((wl * 2 + 1) * 4 + kc) * 64 + lane) * 8);
    }
#pragma unroll
    for (int kc = 0; kc < 3; ++kc) {
      au[kc] = *(const f16x8*)(W + OFF_AX + (((wl * 2 + 0) * 3 + kc) * 64 + lane) * 8);
      ag2[kc] = *(const f16x8*)(W + OFF_AX + (((wl * 2 + 1) * 3 + kc) * 64 + lane) * 8);
    }
    au[3] = (f16x8)(f16)0.f;
    ag2[3] = (f16x8)(f16)0.f;
    const float* cp = ctx + (bg * 16 + c) * 32 + 8 * q;
#pragma unroll
    for (int j = 0; j < 8; ++j) bctx[j] = (f16)cp[j];
  } else {
#pragma unroll
    for (int kc = 0; kc < 4; ++kc) {
      awg[kc] = *(const f16x8*)(W + OFF_A1 + (((wl * 2 + 0) * 4 + kc) * 64 + lane) * 8);
      awr[kc] = *(const f16x8*)(W + OFF_A1 + (((wl * 2 + 1) * 4 + kc) * 64 + lane) * 8);
      au[kc] = *(const f16x8*)(W + OFF_AIO + (((wl * 2 + 0) * 4 + kc) * 64 + lane) * 8);
      ag2[kc] = *(const f16x8*)(W + OFF_AIO + (((wl * 2 + 1) * 4 + kc) * 64 + lane) * 8);
    }
  }

  // per-lane params for the 4 owned rows (packed pairs, itv negated)
  const float* taup = isL0 ? tau0p : tau1p;
  const float* bgp = isL0 ? bg0p : bg1p;
  f32x2 nitv2[2];
  f32x4 bgv4;
#pragma unroll
  for (int r = 0; r < 4; ++r) {
    float t = taup[jbase + r];
    nitv2[r >> 1][r & 1] = -1.f / (logf(1.f + __expf(t)) + 1.f);
    bgv4[r] = bgp[jbase + r];
  }

  f32x2 hst2[2], hhc2[2], ksum2[2], u2[2];
  f32x4 ga, ra, gx4, un4, gxn4;
#pragma unroll
  for (int p = 0; p < 2; ++p) {
    hst2[p] = ZERO2;
    hhc2[p] = ZERO2;
    ksum2[p] = ZERO2;
    u2[p] = ZERO2;
  }
  gx4 = ZERO4;
  un4 = ZERO4;
  gxn4 = ZERO4;

  // zero initial-state buffers: hq1 (h0 at t=-1) and l1h (h1 at t=-1)
  for (int j = tid; j < 2176; j += 1024) {
    hq1[j] = (f16)0.f;
    l1h[j] = (f16)0.f;
  }
  // pre-stage x(0): 256 threads (all in L0 waves 0-3), float4 each
  const int bs = tid >> 4, fp = tid & 15;
  const size_t seqrow = ((size_t)(bg * 16 + bs)) * NSTEP * 64 + 4 * fp;
  float4 sq_nxt = {0.f, 0.f, 0.f, 0.f};
  float4 sq_ld = sq_nxt;
  if (tid < 256) {
    float4 sv = *(const float4*)(seq + seqrow);
    *(f16x4*)(xt0 + bs * 72 + 4 * fp) =
        (f16x4){(f16)sv.x, (f16)sv.y, (f16)sv.z, (f16)sv.w};
    sq_nxt = *(const float4*)(seq + seqrow + 64);  // x(1)
  }
  __syncthreads();
  // u/gx for step 0 (pipeline warm-up)
  if (isL0) {
    XPROJ(xt0, un4, gxn4);
    u2[0] = (f32x2){un4[0], un4[1]};
    u2[1] = (f32x2){un4[2], un4[3]};
    gx4 = gxn4;
  }

#pragma unroll 1
  for (int i = 0; i <= NSTEP; ++i) {
    const f16* hprev = ((i + 1) & 1) ? hq1 : hq0;  // h0(t-1) buffer
    f16* xw = ((i + 1) & 1) ? xt1 : xt0;           // buffer for x(i+1)

    // ===== slot A: L0 stage1 (+stage x(i+1), issue x(i+2)) | L1 io + stage1
    if (isL0) {
      if (i < NSTEP) {
        if (tid < 256 && i + 2 < NSTEP)
          sq_ld = *(const float4*)(seq + seqrow + (size_t)(i + 2) * 64);
        MM2G(hprev);  // stage 1 on h0(t-1) -- the critical prefix
        if (tid < 256 && i + 1 < NSTEP)
          *(f16x4*)(xw + bs * 72 + 4 * fp) =
              (f16x4){(f16)sq_nxt.x, (f16)sq_nxt.y, (f16)sq_nxt.z, (f16)sq_nxt.w};
        GATEP(1.0f, 0.5f, bufA, 1);
      }
    } else {
      if (i >= 1) {
        MMIO_B(hprev);  // u1 = Win1*h0_new, g1x = bg + Wg1x*h0_new
        u2[0] = (f32x2){ga[0], ga[1]};
        u2[1] = (f32x2){ga[2], ga[3]};
        gx4 = ra;
        MM2G(l1h);  // stage 1 on h1(t-2)
        GATEP(1.0f, 0.5f, bufA, 1);
      }
    }
    BAR();

    // ===== slot B: stage 2 ; L0 also computes x-proj(i+1) off-path =====
    if (isL0) {
      if (i < NSTEP) {
        MM2G(bufA);
        GATEP(2.0f, 0.5f, bufB, 0);
        if (i + 1 < NSTEP) { XPROJ(xw, un4, gxn4); }
      }
    } else if (i >= 1) {
      MM2G(bufA);
      GATEP(2.0f, 0.5f, bufB, 0);
    }
    BAR();

    // ===== slot C: stage 3 =====
    if ((isL0 && i < NSTEP) || (!isL0 && i >= 1)) {
      MM2G(bufB);
      GATEP(2.0f, 1.0f, bufA, 0);
    }
    BAR();

    // ===== slot D: stage 4 -> h_new; L0 commits pipelined u/gx + seq reg =====
    if (isL0) {
      if (i < NSTEP) {
        MM2G(bufA);
        GATEF((i & 1) ? hq1 : hq0);
        if (i + 1 < NSTEP) {
          u2[0] = (f32x2){un4[0], un4[1]};
          u2[1] = (f32x2){un4[2], un4[3]};
          gx4 = gxn4;
          if (i + 2 < NSTEP) sq_nxt = sq_ld;
        }
      }
    } else if (i >= 1) {
      MM2G(bufA);
      GATEF(l1h);
    }
    BAR();
  }

  // ======================= classifier epilogue ===========================
  float* h1f = (float*)smem;  // [16][132] f32
  if (!isL0) {
#pragma unroll
    for (int p = 0; p < 2; ++p)
      *(f32x2*)(h1f + c * 132 + jbase + 2 * p) = hst2[p];
  }
  __syncthreads();
  float* z1 = (float*)(smem + 16 * 132 * 4);  // [16][64] f32
  {
    int b = tid >> 5, o = tid & 31;
    if (b < 16) {
#pragma unroll
      for (int hlf = 0; hlf < 2; ++hlf) {
        int oo = o + 32 * hlf;
        const float* wr = W1 + oo * 128;
        const float* hr = h1f + b * 132;
        float s = 0.f;
#pragma unroll
        for (int j = 0; j < 128; j += 4) {
          f32x4 wv = *(const f32x4*)(wr + j);
          f32x4 hv = *(const f32x4*)(hr + j);
          s += wv[0] * hv[0] + wv[1] * hv[1] + wv[2] * hv[2] + wv[3] * hv[3];
        }
        s += b1[oo];
        z1[b * 64 + oo] = fmaxf(s, 0.f);
      }
    }
  }
  __syncthreads();
  if (tid < 16) {
    float s = b2[0];
#pragma unroll
    for (int o = 0; o < 64; ++o) s += z1[tid * 64 + o] * W2[o];
    out[bg * 16 + tid] = rcp_f(1.f + __expf(-s));
  }
}

extern "C" void kernel_launch(void* const* d_in, const int* in_sizes, int n_in,
                              void* d_out, int out_size, void* d_ws, size_t ws_size,
                              hipStream_t stream) {
  (void)in_sizes; (void)n_in; (void)out_size; (void)ws_size;
  const float* seq = (const float*)d_in[0];
  const float* ctx = (const float*)d_in[1];
  const float* tau0 = (const float*)d_in[2];
  const float* Win0 = (const float*)d_in[3];
  const float* Wrec0 = (const float*)d_in[4];
  const float* Wg0 = (const float*)d_in[5];
  const float* bg0 = (const float*)d_in[6];
  const float* tau1 = (const float*)d_in[7];
  const float* Win1 = (const float*)d_in[8];
  const float* Wrec1 = (const float*)d_in[9];
  const float* Wg1 = (const float*)d_in[10];
  const float* bg1 = (const float*)d_in[11];
  const float* W1 = (const float*)d_in[12];
  const float* b1 = (const float*)d_in[13];
  const float* W2 = (const float*)d_in[14];
  const float* b2 = (const float*)d_in[15];
  f16* W = (f16*)d_ws;  // 245760 B of packed fragments

  prep_kernel<<<480, 256, 0, stream>>>(Win0, Wrec0, Wg0, Win1, Wrec1, Wg1, W);
  ltc_kernel<<<32, 1024, 0, stream>>>(seq, ctx, tau0, bg0, tau1, bg1, W1, b1,
                                      W2, b2, W, (float*)d_out);
}

// Round 10
// 1753.942 us; speedup vs baseline: 1.5770x; 1.5736x over previous
//
#include <hip/hip_runtime.h>

// LTC RNN (LiquidNeuralNetwork): B=512, S=512, H=128, 2 layers, RK4.
// Round 12: revert to round-8 base (1750us: 512 thr, 2 tiles/wave, packed-f32
// gate) + EVEN/ODD STEP UNROLL. Rounds 9-11 proved the compiler won't allocate
// >64 VGPR at 1024-thread blocks (spill -> 2720us) -> 16-wave TLP branch dead.
// r8 counters: active-CU issue ~83% (54% VALU + 29% MFMA); remaining levers are
// issue-count reductions. This round: peel i=0 and i=512, unroll the loop in
// (odd,even) pairs so hq0/hq1, xt0/xt1, h-dst are compile-time per body (kills
// per-iter pointer cndmask+adds), and hoist all LDS byte offsets (bro/jo/xro).
// Kept: lag-1 layer pipeline (waves 0-3 L0 @t, 4-7 L1 @t-1), 4 slots/step,
// lgkm-only barriers, x-proj pipelined into slot B, gx/bg folded into MFMA
// C-init, f16 fragment pack, (512,1) bounds.

typedef _Float16 f16;
typedef _Float16 f16x4 __attribute__((ext_vector_type(4)));
typedef _Float16 f16x8 __attribute__((ext_vector_type(8)));
typedef float f32x2 __attribute__((ext_vector_type(2)));
typedef float f32x4 __attribute__((ext_vector_type(4)));

#define NSTEP 512
#define OFF_A0 0
#define OFF_A1 32768
#define OFF_AIO 65536
#define OFF_AX 98304
#define W_TOTAL 122880

// LDS byte offsets. hh buffers: [16 cols][136 f16] = 4352 B each.
#define HQ0 0
#define HQ1 4352
#define L0A 8704
#define L0B 13056
#define L1A 17408
#define L1B 21760
#define L1H 26112
#define XT0 30464
#define XT1 32768
#define SMEM_BYTES 35072

__device__ __forceinline__ float rcp_f(float x) { return __builtin_amdgcn_rcpf(x); }

#define FMA2(A, B, C) __builtin_elementwise_fma((A), (B), (C))
#define B2(X) ((f32x2){(X), (X)})
#define ZERO4 ((f32x4){0.f, 0.f, 0.f, 0.f})
#define ZERO2 ((f32x2){0.f, 0.f})

// packed tanh: pk add + 2 scalar exp + pk add + 2 rcp + pk fma
__device__ __forceinline__ f32x2 tanh2_f(f32x2 z) {
  f32x2 zz = z + z;
  f32x2 e = {__expf(zz[0]), __expf(zz[1])};
  f32x2 d = e + 1.f;
  f32x2 r = {rcp_f(d[0]), rcp_f(d[1])};
  return FMA2(r, B2(-2.f), B2(1.f));
}
// packed sigmoid(t), t in [-1,1]: odd Taylor of 0.5+0.5*tanh(t/2), |err|<3e-6
__device__ __forceinline__ f32x2 sig2_f(f32x2 t) {
  f32x2 s = t * t;
  f32x2 p = FMA2(s, B2(2.1356861e-5f), B2(-2.1081349e-4f));
  p = FMA2(s, p, B2(2.0833333e-3f));
  p = FMA2(s, p, B2(-2.0833333e-2f));
  p = FMA2(s, p, B2(0.25f));
  return FMA2(t, p, B2(0.5f));
}

// lgkm-only barrier: LDS produce->consume needs lgkmcnt(0)+s_barrier only;
// does NOT drain vmcnt (seq prefetch stays in flight across barriers).
#define BAR()                                            \
  do {                                                   \
    asm volatile("s_waitcnt lgkmcnt(0)" ::: "memory");   \
    __builtin_amdgcn_s_barrier();                        \
  } while (0)

// Pack all recurrent-loop weights into f16 MFMA A-fragments.
// A-frag (16x16x32): A[m=lane&15][k=(lane>>4)*8+j], row-tile T = rows 16T..16T+15.
// A0 @0      [T8][sel2][kc4][lane64][j8]  sel0=Wg0 h-part, sel1=Wrec0
// A1 @32768  same                          sel0=Wg1 h-part, sel1=Wrec1
// AIO@65536  same                          sel0=Win1,       sel1=Wg1 x-part
// AX @98304  [T8][sel2][kc3][lane64][j8]  sel0=Win0,       sel1=Wg0 x-part (K=96)
__global__ __launch_bounds__(256) void prep_kernel(
    const float* __restrict__ Win0, const float* __restrict__ Wrec0,
    const float* __restrict__ Wg0, const float* __restrict__ Win1,
    const float* __restrict__ Wrec1, const float* __restrict__ Wg1,
    f16* __restrict__ W) {
  int i = blockIdx.x * 256 + threadIdx.x;
  if (i >= W_TOTAL) return;
  if (i < OFF_AX) {
    int sec = i >> 15;
    int r = i & 32767;
    int j = r & 7, lane = (r >> 3) & 63, kc = (r >> 9) & 3, sel = (r >> 11) & 1,
        w = (r >> 12) & 7;
    int row = w * 16 + (lane & 15);
    int k = kc * 32 + ((lane >> 4) << 3) + j;
    float v;
    if (sec == 0)
      v = sel ? Wrec0[row * 128 + k] : Wg0[row * 224 + 96 + k];
    else if (sec == 1)
      v = sel ? Wrec1[row * 128 + k] : Wg1[row * 256 + 128 + k];
    else
      v = sel ? Wg1[row * 256 + k] : Win1[row * 128 + k];
    W[i] = (f16)v;
  } else {
    int r = i - OFF_AX;
    int j = r & 7, lane = (r >> 3) & 63, g = r >> 9;
    int kc = g % 3, sg = g / 3;
    int sel = sg & 1, w = sg >> 1;
    int row = w * 16 + (lane & 15);
    int k = kc * 32 + ((lane >> 4) << 3) + j;
    W[i] = (f16)(sel ? Wg0[row * 224 + k] : Win0[row * 96 + k]);
  }
}

#define MFMA16(A, B, C) __builtin_amdgcn_mfma_f32_16x16x32_f16((A), (B), (C), 0, 0, 0)

// recurrent matvec, gx folded into gate C-init: ga = gx4 + Wg_h*h; ra = Wrec*h
#define MM2G(SRC)                                                   \
  {                                                                 \
    ga[0] = gx4[0]; ga[1] = gx4[1];                                 \
    ra[0] = ZERO4; ra[1] = ZERO4;                                   \
    const f16* bp_ = (SRC) + bro;                                   \
    _Pragma("unroll") for (int kc_ = 0; kc_ < 4; ++kc_) {           \
      f16x8 bf_ = *(const f16x8*)(bp_ + kc_ * 32);                  \
      ga[0] = MFMA16(awg[0][kc_], bf_, ga[0]);                      \
      ra[0] = MFMA16(awr[0][kc_], bf_, ra[0]);                      \
      ga[1] = MFMA16(awg[1][kc_], bf_, ga[1]);                      \
      ra[1] = MFMA16(awr[1][kc_], bf_, ra[1]);                      \
    }                                                               \
  }

// L1 io projection, bg folded into ra C-init: ga = Win1*h0; ra = bg + Wg1x*h0
#define MMIO_B(SRC)                                                 \
  {                                                                 \
    ga[0] = ZERO4; ga[1] = ZERO4;                                   \
    ra[0] = bgv4[0]; ra[1] = bgv4[1];                               \
    const f16* bp_ = (SRC) + bro;                                   \
    _Pragma("unroll") for (int kc_ = 0; kc_ < 4; ++kc_) {           \
      f16x8 bf_ = *(const f16x8*)(bp_ + kc_ * 32);                  \
      ga[0] = MFMA16(au[0][kc_], bf_, ga[0]);                       \
      ra[0] = MFMA16(ag2[0][kc_], bf_, ra[0]);                      \
      ga[1] = MFMA16(au[1][kc_], bf_, ga[1]);                       \
      ra[1] = MFMA16(ag2[1][kc_], bf_, ra[1]);                      \
    }                                                               \
  }

// L0 x-projection (K=96: 2 chunks from x-tile + ctx), bg folded:
// UD = Win0*x; GD = bg + Wg0x*x
#define XPROJ(XSRC, UD, GD)                                         \
  {                                                                 \
    f32x4 tg_[2], tr_[2];                                           \
    tg_[0] = ZERO4; tg_[1] = ZERO4;                                 \
    tr_[0] = bgv4[0]; tr_[1] = bgv4[1];                             \
    f16x8 bx0_ = *(const f16x8*)((XSRC) + xro);                     \
    f16x8 bx1_ = *(const f16x8*)((XSRC) + xro + 32);                \
    _Pragma("unroll") for (int i2_ = 0; i2_ < 2; ++i2_) {           \
      tg_[i2_] = MFMA16(au[i2_][0], bx0_, tg_[i2_]);                \
      tr_[i2_] = MFMA16(ag2[i2_][0], bx0_, tr_[i2_]);               \
      tg_[i2_] = MFMA16(au[i2_][1], bx1_, tg_[i2_]);                \
      tr_[i2_] = MFMA16(ag2[i2_][1], bx1_, tr_[i2_]);               \
      tg_[i2_] = MFMA16(au[i2_][2], bctx, tg_[i2_]);                \
      tr_[i2_] = MFMA16(ag2[i2_][2], bctx, tr_[i2_]);               \
      (UD)[i2_] = tg_[i2_];                                         \
      (GD)[i2_] = tr_[i2_];                                         \
    }                                                               \
  }

// RK stage body, packed pairs. Gate arg is complete in ga (gx folded).
// FIRST=1: ksum = kk (stage 1). Else ksum += WC*kk.
#define GATEP(WC, HC, DST, FIRST)                                   \
  _Pragma("unroll") for (int i2_ = 0; i2_ < 2; ++i2_) {             \
    f16x4 hv_;                                                      \
    _Pragma("unroll") for (int p_ = 0; p_ < 2; ++p_) {              \
      f32x2 z_ = p_ ? (f32x2){ga[i2_][2], ga[i2_][3]}               \
                    : (f32x2){ga[i2_][0], ga[i2_][1]};              \
      f32x2 rr_ = p_ ? (f32x2){ra[i2_][2], ra[i2_][3]}              \
                     : (f32x2){ra[i2_][0], ra[i2_][1]};             \
      f32x2 th_ = tanh2_f(z_);                                      \
      f32x2 gt_ = sig2_f(th_);                                      \
      f32x2 kk_ = FMA2(gt_, rr_,                                    \
                       FMA2(nitv2[i2_][p_], hhc2[i2_][p_], u2[i2_][p_])); \
      ksum2[i2_][p_] = (FIRST) ? kk_ : FMA2(B2(WC), kk_, ksum2[i2_][p_]); \
      f32x2 hn_ = FMA2(B2(HC), kk_, hst2[i2_][p_]);                 \
      hhc2[i2_][p_] = hn_;                                          \
      hv_[2 * p_] = (f16)hn_[0];                                    \
      hv_[2 * p_ + 1] = (f16)hn_[1];                                \
    }                                                               \
    *(f16x4*)((DST) + jo[i2_]) = hv_;                               \
  }

// RK stage 4: h_new = tanh(h + (ksum+kk)/6) -> state + next stage-1 eval.
#define GATEF(DST)                                                  \
  _Pragma("unroll") for (int i2_ = 0; i2_ < 2; ++i2_) {             \
    f16x4 hv_;                                                      \
    _Pragma("unroll") for (int p_ = 0; p_ < 2; ++p_) {              \
      f32x2 z_ = p_ ? (f32x2){ga[i2_][2], ga[i2_][3]}               \
                    : (f32x2){ga[i2_][0], ga[i2_][1]};              \
      f32x2 rr_ = p_ ? (f32x2){ra[i2_][2], ra[i2_][3]}              \
                     : (f32x2){ra[i2_][0], ra[i2_][1]};             \
      f32x2 th_ = tanh2_f(z_);                                      \
      f32x2 gt_ = sig2_f(th_);                                      \
      f32x2 kk_ = FMA2(gt_, rr_, FMA2(nitv2[i2_][p_], hhc2[i2_][p_], u2[i2_][p_])); \
      f32x2 ks_ = ksum2[i2_][p_] + kk_;                             \
      f32x2 hn_ = tanh2_f(FMA2(B2(0.16666667f), ks_, hst2[i2_][p_])); \
      hst2[i2_][p_] = hn_;                                          \
      hhc2[i2_][p_] = hn_;                                          \
      hv_[2 * p_] = (f16)hn_[0];                                    \
      hv_[2 * p_ + 1] = (f16)hn_[1];                                \
    }                                                               \
    *(f16x4*)((DST) + jo[i2_]) = hv_;                               \
  }

// one full step: 4 slots + 4 barriers. HPREV/XW/HDST are compile-time
// pointers per parity; L0ON/L1ON are wave-uniform guards.
#define STEP(I, HPREV, XW, HDST, L0ON, L1ON)                              \
  {                                                                       \
    if (isL0) {                                                           \
      if (L0ON) {                                                         \
        if (tid < 256 && (I) + 2 < NSTEP)                                 \
          sq_ld = *(const float4*)(seq + seqrow + (size_t)((I) + 2) * 64);\
        MM2G(HPREV);                                                      \
        if (tid < 256 && (I) + 1 < NSTEP)                                 \
          *(f16x4*)((XW) + xoff) =                                        \
              (f16x4){(f16)sq_nxt.x, (f16)sq_nxt.y, (f16)sq_nxt.z,        \
                      (f16)sq_nxt.w};                                     \
        GATEP(1.0f, 0.5f, bufA, 1);                                       \
      }                                                                   \
    } else if (L1ON) {                                                    \
      MMIO_B(HPREV);                                                      \
      _Pragma("unroll") for (int i2 = 0; i2 < 2; ++i2) {                  \
        u2[i2][0] = (f32x2){ga[i2][0], ga[i2][1]};                        \
        u2[i2][1] = (f32x2){ga[i2][2], ga[i2][3]};                        \
        gx4[i2] = ra[i2];                                                 \
      }                                                                   \
      MM2G(l1h);                                                          \
      GATEP(1.0f, 0.5f, bufA, 1);                                         \
    }                                                                     \
    BAR();                                                                \
    if (isL0) {                                                           \
      if (L0ON) {                                                         \
        MM2G(bufA);                                                       \
        GATEP(2.0f, 0.5f, bufB, 0);                                       \
        if ((I) + 1 < NSTEP) { XPROJ(XW, un4, gxn4); }                    \
      }                                                                   \
    } else if (L1ON) {                                                    \
      MM2G(bufA);                                                         \
      GATEP(2.0f, 0.5f, bufB, 0);                                         \
    }                                                                     \
    BAR();                                                                \
    if ((isL0 && (L0ON)) || (!isL0 && (L1ON))) {                          \
      MM2G(bufB);                                                         \
      GATEP(2.0f, 1.0f, bufA, 0);                                         \
    }                                                                     \
    BAR();                                                                \
    if (isL0) {                                                           \
      if (L0ON) {                                                         \
        MM2G(bufA);                                                       \
        GATEF(HDST);                                                      \
        if ((I) + 1 < NSTEP) {                                            \
          _Pragma("unroll") for (int i2 = 0; i2 < 2; ++i2) {              \
            u2[i2][0] = (f32x2){un4[i2][0], un4[i2][1]};                  \
            u2[i2][1] = (f32x2){un4[i2][2], un4[i2][3]};                  \
            gx4[i2] = gxn4[i2];                                           \
          }                                                               \
          if ((I) + 2 < NSTEP) sq_nxt = sq_ld;                            \
        }                                                                 \
      }                                                                   \
    } else if (L1ON) {                                                    \
      MM2G(bufA);                                                         \
      GATEF(l1h);                                                         \
    }                                                                     \
    BAR();                                                                \
  }

__global__ __launch_bounds__(512, 1) void ltc_kernel(
    const float* __restrict__ seq, const float* __restrict__ ctx,
    const float* __restrict__ tau0p, const float* __restrict__ bg0p,
    const float* __restrict__ tau1p, const float* __restrict__ bg1p,
    const float* __restrict__ W1, const float* __restrict__ b1,
    const float* __restrict__ W2, const float* __restrict__ b2,
    const f16* __restrict__ W, float* __restrict__ out) {
  __shared__ __align__(16) char smem[SMEM_BYTES];
  f16* hq0 = (f16*)(smem + HQ0);
  f16* hq1 = (f16*)(smem + HQ1);
  f16* l0a = (f16*)(smem + L0A);
  f16* l0b = (f16*)(smem + L0B);
  f16* l1a = (f16*)(smem + L1A);
  f16* l1b = (f16*)(smem + L1B);
  f16* l1h = (f16*)(smem + L1H);
  f16* xt0 = (f16*)(smem + XT0);
  f16* xt1 = (f16*)(smem + XT1);

  const int tid = threadIdx.x;
  const int w8 = tid >> 6, lane = tid & 63;
  const int q = lane >> 4, c = lane & 15;
  const int wl = w8 & 3;
  const bool isL0 = (w8 < 4);
  const int bg = blockIdx.x;
  int jb[2];
  jb[0] = 32 * wl + 4 * q;
  jb[1] = jb[0] + 16;
  // hoisted LDS offsets (loop-invariant)
  const int bro = c * 136 + 8 * q;   // B-frag read offset in hh buffers
  const int xro = c * 72 + 8 * q;    // x-tile read offset
  int jo[2];
  jo[0] = c * 136 + jb[0];           // gate write offsets
  jo[1] = c * 136 + jb[1];
  const int bs = tid >> 4, fp = tid & 15;
  const int xoff = bs * 72 + 4 * fp; // x-tile stage offset

  f16* bufA = isL0 ? l0a : l1a;
  f16* bufB = isL0 ? l0b : l1b;

  // ---- weight fragments -> VGPRs (held for whole kernel) ----
  f16x8 awg[2][4], awr[2][4], au[2][4], ag2[2][4];
  f16x8 bctx;
  if (isL0) {
#pragma unroll
    for (int i2 = 0; i2 < 2; ++i2) {
      int T = 2 * wl + i2;
#pragma unroll
      for (int kc = 0; kc < 4; ++kc) {
        awg[i2][kc] = *(const f16x8*)(W + OFF_A0 + (((T * 2 + 0) * 4 + kc) * 64 + lane) * 8);
        awr[i2][kc] = *(const f16x8*)(W + OFF_A0 + (((T * 2 + 1) * 4 + kc) * 64 + lane) * 8);
      }
#pragma unroll
      for (int kc = 0; kc < 3; ++kc) {
        au[i2][kc] = *(const f16x8*)(W + OFF_AX + (((T * 2 + 0) * 3 + kc) * 64 + lane) * 8);
        ag2[i2][kc] = *(const f16x8*)(W + OFF_AX + (((T * 2 + 1) * 3 + kc) * 64 + lane) * 8);
      }
      au[i2][3] = (f16x8)(f16)0.f;
      ag2[i2][3] = (f16x8)(f16)0.f;
    }
    const float* cp = ctx + (bg * 16 + c) * 32 + 8 * q;
#pragma unroll
    for (int j = 0; j < 8; ++j) bctx[j] = (f16)cp[j];
  } else {
#pragma unroll
    for (int i2 = 0; i2 < 2; ++i2) {
      int T = 2 * wl + i2;
#pragma unroll
      for (int kc = 0; kc < 4; ++kc) {
        awg[i2][kc] = *(const f16x8*)(W + OFF_A1 + (((T * 2 + 0) * 4 + kc) * 64 + lane) * 8);
        awr[i2][kc] = *(const f16x8*)(W + OFF_A1 + (((T * 2 + 1) * 4 + kc) * 64 + lane) * 8);
        au[i2][kc] = *(const f16x8*)(W + OFF_AIO + (((T * 2 + 0) * 4 + kc) * 64 + lane) * 8);
        ag2[i2][kc] = *(const f16x8*)(W + OFF_AIO + (((T * 2 + 1) * 4 + kc) * 64 + lane) * 8);
      }
    }
  }

  // per-lane params for the 8 owned rows (packed pairs, itv negated)
  const float* taup = isL0 ? tau0p : tau1p;
  const float* bgp = isL0 ? bg0p : bg1p;
  f32x2 nitv2[2][2];
  f32x4 bgv4[2];
#pragma unroll
  for (int i2 = 0; i2 < 2; ++i2)
#pragma unroll
    for (int r = 0; r < 4; ++r) {
      float t = taup[jb[i2] + r];
      nitv2[i2][r >> 1][r & 1] = -1.f / (logf(1.f + __expf(t)) + 1.f);
      bgv4[i2][r] = bgp[jb[i2] + r];
    }

  f32x2 hst2[2][2], hhc2[2][2], ksum2[2][2], u2[2][2];
  f32x4 ga[2], ra[2], gx4[2], un4[2], gxn4[2];
#pragma unroll
  for (int i2 = 0; i2 < 2; ++i2)
#pragma unroll
    for (int p = 0; p < 2; ++p) {
      hst2[i2][p] = ZERO2;
      hhc2[i2][p] = ZERO2;
      ksum2[i2][p] = ZERO2;
      u2[i2][p] = ZERO2;
    }
  gx4[0] = gx4[1] = ZERO4;
  un4[0] = un4[1] = ZERO4;
  gxn4[0] = gxn4[1] = ZERO4;

  // zero initial-state buffers: hq1 (h0 at t=-1) and l1h (h1 at t=-1)
  for (int j = tid; j < 2176; j += 512) {
    hq1[j] = (f16)0.f;
    l1h[j] = (f16)0.f;
  }
  // pre-stage x(0): 256 L0 threads, float4 each
  const size_t seqrow = ((size_t)(bg * 16 + bs)) * NSTEP * 64 + 4 * fp;
  float4 sq_nxt = {0.f, 0.f, 0.f, 0.f};
  float4 sq_ld = sq_nxt;
  if (tid < 256) {
    float4 sv = *(const float4*)(seq + seqrow);
    *(f16x4*)(xt0 + xoff) = (f16x4){(f16)sv.x, (f16)sv.y, (f16)sv.z, (f16)sv.w};
    sq_nxt = *(const float4*)(seq + seqrow + 64);  // x(1)
  }
  __syncthreads();
  // u/gx for step 0 (pipeline warm-up)
  if (isL0) {
    XPROJ(xt0, un4, gxn4);
#pragma unroll
    for (int i2 = 0; i2 < 2; ++i2) {
      u2[i2][0] = (f32x2){un4[i2][0], un4[i2][1]};
      u2[i2][1] = (f32x2){un4[i2][2], un4[i2][3]};
      gx4[i2] = gxn4[i2];
    }
  }

  // i=0 (even parity: hprev=hq1, xw=xt1, hdst=hq0), L1 idle
  STEP(0, hq1, xt1, hq0, true, false);
  // pairs (odd, even): i = 1,3,...,511; partner i+1 = 2,...,512.
  // L0 active for i<NSTEP (all odd bodies; even body off only at i+1=512).
#pragma unroll 1
  for (int i = 1; i < NSTEP; i += 2) {
    STEP(i, hq0, xt0, hq1, true, true);
    STEP(i + 1, hq1, xt1, hq0, (i + 1) < NSTEP, true);
  }

  // ======================= classifier epilogue ===========================
  float* h1f = (float*)smem;  // [16][132] f32
  if (!isL0) {
#pragma unroll
    for (int i2 = 0; i2 < 2; ++i2)
#pragma unroll
      for (int p = 0; p < 2; ++p)
        *(f32x2*)(h1f + c * 132 + jb[i2] + 2 * p) = hst2[i2][p];
  }
  __syncthreads();
  float* z1 = (float*)(smem + 16 * 132 * 4);  // [16][64] f32
  {
    int b = tid >> 5, o = tid & 31;
#pragma unroll
    for (int hlf = 0; hlf < 2; ++hlf) {
      int oo = o + 32 * hlf;
      const float* wr = W1 + oo * 128;
      const float* hr = h1f + b * 132;
      float s = 0.f;
#pragma unroll
      for (int j = 0; j < 128; j += 4) {
        f32x4 wv = *(const f32x4*)(wr + j);
        f32x4 hv = *(const f32x4*)(hr + j);
        s += wv[0] * hv[0] + wv[1] * hv[1] + wv[2] * hv[2] + wv[3] * hv[3];
      }
      s += b1[oo];
      z1[b * 64 + oo] = fmaxf(s, 0.f);
    }
  }
  __syncthreads();
  if (tid < 16) {
    float s = b2[0];
#pragma unroll
    for (int o = 0; o < 64; ++o) s += z1[tid * 64 + o] * W2[o];
    out[bg * 16 + tid] = rcp_f(1.f + __expf(-s));
  }
}

extern "C" void kernel_launch(void* const* d_in, const int* in_sizes, int n_in,
                              void* d_out, int out_size, void* d_ws, size_t ws_size,
                              hipStream_t stream) {
  (void)in_sizes; (void)n_in; (void)out_size; (void)ws_size;
  const float* seq = (const float*)d_in[0];
  const float* ctx = (const float*)d_in[1];
  const float* tau0 = (const float*)d_in[2];
  const float* Win0 = (const float*)d_in[3];
  const float* Wrec0 = (const float*)d_in[4];
  const float* Wg0 = (const float*)d_in[5];
  const float* bg0 = (const float*)d_in[6];
  const float* tau1 = (const float*)d_in[7];
  const float* Win1 = (const float*)d_in[8];
  const float* Wrec1 = (const float*)d_in[9];
  const float* Wg1 = (const float*)d_in[10];
  const float* bg1 = (const float*)d_in[11];
  const float* W1 = (const float*)d_in[12];
  const float* b1 = (const float*)d_in[13];
  const float* W2 = (const float*)d_in[14];
  const float* b2 = (const float*)d_in[15];
  f16* W = (f16*)d_ws;  // 245760 B of packed fragments

  prep_kernel<<<480, 256, 0, stream>>>(Win0, Wrec0, Wg0, Win1, Wrec1, Wg1, W);
  ltc_kernel<<<32, 512, 0, stream>>>(seq, ctx, tau0, bg0, tau1, bg1, W1, b1, W2,
                                     b2, W, (float*)d_out);
}

// Round 12
// 1681.819 us; speedup vs baseline: 1.6447x; 1.0429x over previous
//
#include <hip/hip_runtime.h>

// LTC RNN (LiquidNeuralNetwork): B=512, S=512, H=128, 2 layers, RK4.
// Round 14 = round 13 resubmitted with the cvt_pkrtz TYPE FIX (the builtin
// returns __fp16 ext_vector(2), not _Float16 ext_vector(2); r13 died at
// compile). Experiment unchanged:
//  - u/gx PING-PONG keyed to the even/odd unroll: MMIO_B/XPROJ accumulate
//    DIRECTLY into the u/gx register homes (MFMA C-operand = final dest).
//    Kills the 16-mov slot-A copy (L1) and 16-mov slot-D commit (L0).
//  - v_cvt_pkrtz_f16_f32 packs 2 f32 -> 2 f16 in one instr for all f16
//    stores (eval points + x staging): -8 instr/GATEP. RTZ rounding, <=1ulp.
//  - tanh exp-fold: one packed mul by 2*log2(e) feeds v_exp_f32 directly:
//    -2/pair.
// Kept: lag-1 layer pipeline, 4 slots/step, lgkm-only barriers, x-proj in
// slot B, gx/bg folded into MFMA C-init, even/odd unroll, f16 fragment pack.

typedef _Float16 f16;
typedef __fp16 h16x2 __attribute__((ext_vector_type(2)));  // cvt_pkrtz result
typedef _Float16 f16x4 __attribute__((ext_vector_type(4)));
typedef _Float16 f16x8 __attribute__((ext_vector_type(8)));
typedef float f32x2 __attribute__((ext_vector_type(2)));
typedef float f32x4 __attribute__((ext_vector_type(4)));

#define NSTEP 512
#define OFF_A0 0
#define OFF_A1 32768
#define OFF_AIO 65536
#define OFF_AX 98304
#define W_TOTAL 122880

// LDS byte offsets. hh buffers: [16 cols][136 f16] = 4352 B each.
#define HQ0 0
#define HQ1 4352
#define L0A 8704
#define L0B 13056
#define L1A 17408
#define L1B 21760
#define L1H 26112
#define XT0 30464
#define XT1 32768
#define SMEM_BYTES 35072

__device__ __forceinline__ float rcp_f(float x) { return __builtin_amdgcn_rcpf(x); }

#define FMA2(A, B, C) __builtin_elementwise_fma((A), (B), (C))
#define B2(X) ((f32x2){(X), (X)})
#define ZERO4 ((f32x4){0.f, 0.f, 0.f, 0.f})
#define ZERO2 ((f32x2){0.f, 0.f})

// pack 4 f32 (two f32x2) -> f16x4 via 2x v_cvt_pkrtz_f16_f32
__device__ __forceinline__ f16x4 pk4(f32x2 a, f32x2 b) {
  union { h16x2 h2[2]; f16x4 h4; } u;
  u.h2[0] = __builtin_amdgcn_cvt_pkrtz(a[0], a[1]);
  u.h2[1] = __builtin_amdgcn_cvt_pkrtz(b[0], b[1]);
  return u.h4;
}

// packed tanh: 1 pk_mul + 2 v_exp + 1 pk_add + 2 v_rcp + 1 pk_fma
__device__ __forceinline__ f32x2 tanh2_f(f32x2 z) {
#if __has_builtin(__builtin_amdgcn_exp2f)
  f32x2 zz = z * B2(2.885390081777927f);  // 2*log2(e): exp(2z)=exp2(zz)
  f32x2 e = {__builtin_amdgcn_exp2f(zz[0]), __builtin_amdgcn_exp2f(zz[1])};
#else
  f32x2 zz = z + z;
  f32x2 e = {__expf(zz[0]), __expf(zz[1])};
#endif
  f32x2 d = e + 1.f;
  f32x2 r = {rcp_f(d[0]), rcp_f(d[1])};
  return FMA2(r, B2(-2.f), B2(1.f));
}
// packed sigmoid(t), t in [-1,1]: odd Taylor of 0.5+0.5*tanh(t/2), |err|<3e-6
__device__ __forceinline__ f32x2 sig2_f(f32x2 t) {
  f32x2 s = t * t;
  f32x2 p = FMA2(s, B2(2.1356861e-5f), B2(-2.1081349e-4f));
  p = FMA2(s, p, B2(2.0833333e-3f));
  p = FMA2(s, p, B2(-2.0833333e-2f));
  p = FMA2(s, p, B2(0.25f));
  return FMA2(t, p, B2(0.5f));
}

// lgkm-only barrier: LDS produce->consume needs lgkmcnt(0)+s_barrier only;
// does NOT drain vmcnt (seq prefetch stays in flight across barriers).
#define BAR()                                            \
  do {                                                   \
    asm volatile("s_waitcnt lgkmcnt(0)" ::: "memory");   \
    __builtin_amdgcn_s_barrier();                        \
  } while (0)

// Pack all recurrent-loop weights into f16 MFMA A-fragments.
// A-frag (16x16x32): A[m=lane&15][k=(lane>>4)*8+j], row-tile T = rows 16T..16T+15.
// A0 @0      [T8][sel2][kc4][lane64][j8]  sel0=Wg0 h-part, sel1=Wrec0
// A1 @32768  same                          sel0=Wg1 h-part, sel1=Wrec1
// AIO@65536  same                          sel0=Win1,       sel1=Wg1 x-part
// AX @98304  [T8][sel2][kc3][lane64][j8]  sel0=Win0,       sel1=Wg0 x-part (K=96)
__global__ __launch_bounds__(256) void prep_kernel(
    const float* __restrict__ Win0, const float* __restrict__ Wrec0,
    const float* __restrict__ Wg0, const float* __restrict__ Win1,
    const float* __restrict__ Wrec1, const float* __restrict__ Wg1,
    f16* __restrict__ W) {
  int i = blockIdx.x * 256 + threadIdx.x;
  if (i >= W_TOTAL) return;
  if (i < OFF_AX) {
    int sec = i >> 15;
    int r = i & 32767;
    int j = r & 7, lane = (r >> 3) & 63, kc = (r >> 9) & 3, sel = (r >> 11) & 1,
        w = (r >> 12) & 7;
    int row = w * 16 + (lane & 15);
    int k = kc * 32 + ((lane >> 4) << 3) + j;
    float v;
    if (sec == 0)
      v = sel ? Wrec0[row * 128 + k] : Wg0[row * 224 + 96 + k];
    else if (sec == 1)
      v = sel ? Wrec1[row * 128 + k] : Wg1[row * 256 + 128 + k];
    else
      v = sel ? Wg1[row * 256 + k] : Win1[row * 128 + k];
    W[i] = (f16)v;
  } else {
    int r = i - OFF_AX;
    int j = r & 7, lane = (r >> 3) & 63, g = r >> 9;
    int kc = g % 3, sg = g / 3;
    int sel = sg & 1, w = sg >> 1;
    int row = w * 16 + (lane & 15);
    int k = kc * 32 + ((lane >> 4) << 3) + j;
    W[i] = (f16)(sel ? Wg0[row * 224 + k] : Win0[row * 96 + k]);
  }
}

#define MFMA16(A, B, C) __builtin_amdgcn_mfma_f32_16x16x32_f16((A), (B), (C), 0, 0, 0)

// recurrent matvec, gate-x folded via C-init: ga = G + Wg_h*h; ra = Wrec*h
#define MM2G(SRC, G)                                                \
  {                                                                 \
    ga[0] = (G)[0]; ga[1] = (G)[1];                                 \
    ra[0] = ZERO4; ra[1] = ZERO4;                                   \
    const f16* bp_ = (SRC) + bro;                                   \
    _Pragma("unroll") for (int kc_ = 0; kc_ < 4; ++kc_) {           \
      f16x8 bf_ = *(const f16x8*)(bp_ + kc_ * 32);                  \
      ga[0] = MFMA16(awg[0][kc_], bf_, ga[0]);                      \
      ra[0] = MFMA16(awr[0][kc_], bf_, ra[0]);                      \
      ga[1] = MFMA16(awg[1][kc_], bf_, ga[1]);                      \
      ra[1] = MFMA16(awr[1][kc_], bf_, ra[1]);                      \
    }                                                               \
  }

// L1 io projection, DIRECT into u/gx homes: U = Win1*h0; G = bg + Wg1x*h0
#define MMIO_B(SRC, U, G)                                           \
  {                                                                 \
    (U)[0] = ZERO4; (U)[1] = ZERO4;                                 \
    (G)[0] = bgv4[0]; (G)[1] = bgv4[1];                             \
    const f16* bp_ = (SRC) + bro;                                   \
    _Pragma("unroll") for (int kc_ = 0; kc_ < 4; ++kc_) {           \
      f16x8 bf_ = *(const f16x8*)(bp_ + kc_ * 32);                  \
      (U)[0] = MFMA16(au[0][kc_], bf_, (U)[0]);                     \
      (G)[0] = MFMA16(ag2[0][kc_], bf_, (G)[0]);                    \
      (U)[1] = MFMA16(au[1][kc_], bf_, (U)[1]);                     \
      (G)[1] = MFMA16(ag2[1][kc_], bf_, (G)[1]);                    \
    }                                                               \
  }

// L0 x-projection (K=96: 2 chunks from x-tile + ctx), DIRECT into u/gx homes:
// U = Win0*x; G = bg + Wg0x*x
#define XPROJ(XSRC, U, G)                                           \
  {                                                                 \
    (U)[0] = ZERO4; (U)[1] = ZERO4;                                 \
    (G)[0] = bgv4[0]; (G)[1] = bgv4[1];                             \
    f16x8 bx0_ = *(const f16x8*)((XSRC) + xro);                     \
    f16x8 bx1_ = *(const f16x8*)((XSRC) + xro + 32);                \
    _Pragma("unroll") for (int i2_ = 0; i2_ < 2; ++i2_) {           \
      (U)[i2_] = MFMA16(au[i2_][0], bx0_, (U)[i2_]);                \
      (G)[i2_] = MFMA16(ag2[i2_][0], bx0_, (G)[i2_]);               \
      (U)[i2_] = MFMA16(au[i2_][1], bx1_, (U)[i2_]);                \
      (G)[i2_] = MFMA16(ag2[i2_][1], bx1_, (G)[i2_]);               \
      (U)[i2_] = MFMA16(au[i2_][2], bctx, (U)[i2_]);                \
      (G)[i2_] = MFMA16(ag2[i2_][2], bctx, (G)[i2_]);               \
    }                                                               \
  }

// RK stage body, packed pairs. Gate arg complete in ga (gx folded via C-init).
// FIRST=1: ksum = kk (stage 1). Else ksum += WC*kk. pkrtz f16 packing.
#define GATEP(WC, HC, DST, FIRST, U)                                \
  _Pragma("unroll") for (int i2_ = 0; i2_ < 2; ++i2_) {             \
    f32x2 hn_[2];                                                   \
    _Pragma("unroll") for (int p_ = 0; p_ < 2; ++p_) {              \
      f32x2 z_ = {ga[i2_][2 * p_], ga[i2_][2 * p_ + 1]};            \
      f32x2 rr_ = {ra[i2_][2 * p_], ra[i2_][2 * p_ + 1]};           \
      f32x2 uu_ = {(U)[i2_][2 * p_], (U)[i2_][2 * p_ + 1]};         \
      f32x2 th_ = tanh2_f(z_);                                      \
      f32x2 gt_ = sig2_f(th_);                                      \
      f32x2 kk_ = FMA2(gt_, rr_,                                    \
                       FMA2(nitv2[i2_][p_], hhc2[i2_][p_], uu_));   \
      ksum2[i2_][p_] = (FIRST) ? kk_ : FMA2(B2(WC), kk_, ksum2[i2_][p_]); \
      f32x2 h_ = FMA2(B2(HC), kk_, hst2[i2_][p_]);                  \
      hhc2[i2_][p_] = h_;                                           \
      hn_[p_] = h_;                                                 \
    }                                                               \
    *(f16x4*)((DST) + jo[i2_]) = pk4(hn_[0], hn_[1]);               \
  }

// RK stage 4: h_new = tanh(h + (ksum+kk)/6) -> state + next stage-1 eval.
#define GATEF(DST, U)                                               \
  _Pragma("unroll") for (int i2_ = 0; i2_ < 2; ++i2_) {             \
    f32x2 hn_[2];                                                   \
    _Pragma("unroll") for (int p_ = 0; p_ < 2; ++p_) {              \
      f32x2 z_ = {ga[i2_][2 * p_], ga[i2_][2 * p_ + 1]};            \
      f32x2 rr_ = {ra[i2_][2 * p_], ra[i2_][2 * p_ + 1]};           \
      f32x2 uu_ = {(U)[i2_][2 * p_], (U)[i2_][2 * p_ + 1]};         \
      f32x2 th_ = tanh2_f(z_);                                      \
      f32x2 gt_ = sig2_f(th_);                                      \
      f32x2 kk_ = FMA2(gt_, rr_,                                    \
                       FMA2(nitv2[i2_][p_], hhc2[i2_][p_], uu_));   \
      f32x2 ks_ = ksum2[i2_][p_] + kk_;                             \
      f32x2 h_ = tanh2_f(FMA2(B2(0.16666667f), ks_, hst2[i2_][p_])); \
      hst2[i2_][p_] = h_;                                           \
      hhc2[i2_][p_] = h_;                                           \
      hn_[p_] = h_;                                                 \
    }                                                               \
    *(f16x4*)((DST) + jo[i2_]) = pk4(hn_[0], hn_[1]);               \
  }

// one full step: 4 slots + 4 barriers. HPREV/XW/HDST compile-time pointers
// per parity; UC/GC = this step's u/gx home, UN/GN = next step's (ping-pong).
#define STEP(I, HPREV, XW, HDST, UC, GC, UN, GN, L0ON, L1ON)              \
  {                                                                       \
    if (isL0) {                                                           \
      if (L0ON) {                                                         \
        if (tid < 256 && (I) + 2 < NSTEP)                                 \
          sq_ld = *(const float4*)(seq + seqrow + (size_t)((I) + 2) * 64);\
        MM2G(HPREV, GC);                                                  \
        if (tid < 256 && (I) + 1 < NSTEP) {                               \
          f32x2 sa_ = {sq_nxt.x, sq_nxt.y};                               \
          f32x2 sb_ = {sq_nxt.z, sq_nxt.w};                               \
          *(f16x4*)((XW) + xoff) = pk4(sa_, sb_);                         \
        }                                                                 \
        GATEP(1.0f, 0.5f, bufA, 1, UC);                                   \
      }                                                                   \
    } else if (L1ON) {                                                    \
      MMIO_B(HPREV, UC, GC);                                              \
      MM2G(l1h, GC);                                                      \
      GATEP(1.0f, 0.5f, bufA, 1, UC);                                     \
    }                                                                     \
    BAR();                                                                \
    if (isL0) {                                                           \
      if (L0ON) {                                                         \
        MM2G(bufA, GC);                                                   \
        GATEP(2.0f, 0.5f, bufB, 0, UC);                                   \
        if ((I) + 1 < NSTEP) { XPROJ(XW, UN, GN); }                       \
      }                                                                   \
    } else if (L1ON) {                                                    \
      MM2G(bufA, GC);                                                     \
      GATEP(2.0f, 0.5f, bufB, 0, UC);                                     \
    }                                                                     \
    BAR();                                                                \
    if ((isL0 && (L0ON)) || (!isL0 && (L1ON))) {                          \
      MM2G(bufB, GC);                                                     \
      GATEP(2.0f, 1.0f, bufA, 0, UC);                                     \
    }                                                                     \
    BAR();                                                                \
    if (isL0) {                                                           \
      if (L0ON) {                                                         \
        MM2G(bufA, GC);                                                   \
        GATEF(HDST, UC);                                                  \
        if ((I) + 2 < NSTEP) sq_nxt = sq_ld;                              \
      }                                                                   \
    } else if (L1ON) {                                                    \
      MM2G(bufA, GC);                                                     \
      GATEF(l1h, UC);                                                     \
    }                                                                     \
    BAR();                                                                \
  }

__global__ __launch_bounds__(512, 1) void ltc_kernel(
    const float* __restrict__ seq, const float* __restrict__ ctx,
    const float* __restrict__ tau0p, const float* __restrict__ bg0p,
    const float* __restrict__ tau1p, const float* __restrict__ bg1p,
    const float* __restrict__ W1, const float* __restrict__ b1,
    const float* __restrict__ W2, const float* __restrict__ b2,
    const f16* __restrict__ W, float* __restrict__ out) {
  __shared__ __align__(16) char smem[SMEM_BYTES];
  f16* hq0 = (f16*)(smem + HQ0);
  f16* hq1 = (f16*)(smem + HQ1);
  f16* l0a = (f16*)(smem + L0A);
  f16* l0b = (f16*)(smem + L0B);
  f16* l1a = (f16*)(smem + L1A);
  f16* l1b = (f16*)(smem + L1B);
  f16* l1h = (f16*)(smem + L1H);
  f16* xt0 = (f16*)(smem + XT0);
  f16* xt1 = (f16*)(smem + XT1);

  const int tid = threadIdx.x;
  const int w8 = tid >> 6, lane = tid & 63;
  const int q = lane >> 4, c = lane & 15;
  const int wl = w8 & 3;
  const bool isL0 = (w8 < 4);
  const int bg = blockIdx.x;
  int jb[2];
  jb[0] = 32 * wl + 4 * q;
  jb[1] = jb[0] + 16;
  // hoisted LDS offsets (loop-invariant)
  const int bro = c * 136 + 8 * q;   // B-frag read offset in hh buffers
  const int xro = c * 72 + 8 * q;    // x-tile read offset
  int jo[2];
  jo[0] = c * 136 + jb[0];           // gate write offsets
  jo[1] = c * 136 + jb[1];
  const int bs = tid >> 4, fp = tid & 15;
  const int xoff = bs * 72 + 4 * fp; // x-tile stage offset

  f16* bufA = isL0 ? l0a : l1a;
  f16* bufB = isL0 ? l0b : l1b;

  // ---- weight fragments -> VGPRs (held for whole kernel) ----
  f16x8 awg[2][4], awr[2][4], au[2][4], ag2[2][4];
  f16x8 bctx;
  if (isL0) {
#pragma unroll
    for (int i2 = 0; i2 < 2; ++i2) {
      int T = 2 * wl + i2;
#pragma unroll
      for (int kc = 0; kc < 4; ++kc) {
        awg[i2][kc] = *(const f16x8*)(W + OFF_A0 + (((T * 2 + 0) * 4 + kc) * 64 + lane) * 8);
        awr[i2][kc] = *(const f16x8*)(W + OFF_A0 + (((T * 2 + 1) * 4 + kc) * 64 + lane) * 8);
      }
#pragma unroll
      for (int kc = 0; kc < 3; ++kc) {
        au[i2][kc] = *(const f16x8*)(W + OFF_AX + (((T * 2 + 0) * 3 + kc) * 64 + lane) * 8);
        ag2[i2][kc] = *(const f16x8*)(W + OFF_AX + (((T * 2 + 1) * 3 + kc) * 64 + lane) * 8);
      }
      au[i2][3] = (f16x8)(f16)0.f;
      ag2[i2][3] = (f16x8)(f16)0.f;
    }
    const float* cp = ctx + (bg * 16 + c) * 32 + 8 * q;
#pragma unroll
    for (int j = 0; j < 8; ++j) bctx[j] = (f16)cp[j];
  } else {
#pragma unroll
    for (int i2 = 0; i2 < 2; ++i2) {
      int T = 2 * wl + i2;
#pragma unroll
      for (int kc = 0; kc < 4; ++kc) {
        awg[i2][kc] = *(const f16x8*)(W + OFF_A1 + (((T * 2 + 0) * 4 + kc) * 64 + lane) * 8);
        awr[i2][kc] = *(const f16x8*)(W + OFF_A1 + (((T * 2 + 1) * 4 + kc) * 64 + lane) * 8);
        au[i2][kc] = *(const f16x8*)(W + OFF_AIO + (((T * 2 + 0) * 4 + kc) * 64 + lane) * 8);
        ag2[i2][kc] = *(const f16x8*)(W + OFF_AIO + (((T * 2 + 1) * 4 + kc) * 64 + lane) * 8);
      }
    }
  }

  // per-lane params for the 8 owned rows (packed pairs, itv negated)
  const float* taup = isL0 ? tau0p : tau1p;
  const float* bgp = isL0 ? bg0p : bg1p;
  f32x2 nitv2[2][2];
  f32x4 bgv4[2];
#pragma unroll
  for (int i2 = 0; i2 < 2; ++i2)
#pragma unroll
    for (int r = 0; r < 4; ++r) {
      float t = taup[jb[i2] + r];
      nitv2[i2][r >> 1][r & 1] = -1.f / (logf(1.f + __expf(t)) + 1.f);
      bgv4[i2][r] = bgp[jb[i2] + r];
    }

  f32x2 hst2[2][2], hhc2[2][2], ksum2[2][2];
  f32x4 ga[2], ra[2], u4a[2], gx4a[2], u4b[2], gx4b[2];
#pragma unroll
  for (int i2 = 0; i2 < 2; ++i2) {
#pragma unroll
    for (int p = 0; p < 2; ++p) {
      hst2[i2][p] = ZERO2;
      hhc2[i2][p] = ZERO2;
      ksum2[i2][p] = ZERO2;
    }
    u4a[i2] = ZERO4; gx4a[i2] = ZERO4;
    u4b[i2] = ZERO4; gx4b[i2] = ZERO4;
  }

  // zero initial-state buffers: hq1 (h0 at t=-1) and l1h (h1 at t=-1)
  for (int j = tid; j < 2176; j += 512) {
    hq1[j] = (f16)0.f;
    l1h[j] = (f16)0.f;
  }
  // pre-stage x(0): 256 L0 threads, float4 each
  const size_t seqrow = ((size_t)(bg * 16 + bs)) * NSTEP * 64 + 4 * fp;
  float4 sq_nxt = {0.f, 0.f, 0.f, 0.f};
  float4 sq_ld = sq_nxt;
  if (tid < 256) {
    float4 sv = *(const float4*)(seq + seqrow);
    f32x2 sa = {sv.x, sv.y};
    f32x2 sb = {sv.z, sv.w};
    *(f16x4*)(xt0 + xoff) = pk4(sa, sb);
    sq_nxt = *(const float4*)(seq + seqrow + 64);  // x(1)
  }
  __syncthreads();
  // u/gx for step 0 directly into the even-step home (pipeline warm-up)
  if (isL0) { XPROJ(xt0, u4a, gx4a); }

  // i=0 (even: hprev=hq1, xw=xt1, hdst=hq0; UC=a, UN=b), L1 idle
  STEP(0, hq1, xt1, hq0, u4a, gx4a, u4b, gx4b, true, false);
  // pairs (odd, even): odd steps read b / write a; even steps read a / write b.
#pragma unroll 1
  for (int i = 1; i < NSTEP; i += 2) {
    STEP(i, hq0, xt0, hq1, u4b, gx4b, u4a, gx4a, true, true);
    STEP(i + 1, hq1, xt1, hq0, u4a, gx4a, u4b, gx4b, (i + 1) < NSTEP, true);
  }

  // ======================= classifier epilogue ===========================
  float* h1f = (float*)smem;  // [16][132] f32
  if (!isL0) {
#pragma unroll
    for (int i2 = 0; i2 < 2; ++i2)
#pragma unroll
      for (int p = 0; p < 2; ++p)
        *(f32x2*)(h1f + c * 132 + jb[i2] + 2 * p) = hst2[i2][p];
  }
  __syncthreads();
  float* z1 = (float*)(smem + 16 * 132 * 4);  // [16][64] f32
  {
    int b = tid >> 5, o = tid & 31;
#pragma unroll
    for (int hlf = 0; hlf < 2; ++hlf) {
      int oo = o + 32 * hlf;
      const float* wr = W1 + oo * 128;
      const float* hr = h1f + b * 132;
      float s = 0.f;
#pragma unroll
      for (int j = 0; j < 128; j += 4) {
        f32x4 wv = *(const f32x4*)(wr + j);
        f32x4 hv = *(const f32x4*)(hr + j);
        s += wv[0] * hv[0] + wv[1] * hv[1] + wv[2] * hv[2] + wv[3] * hv[3];
      }
      s += b1[oo];
      z1[b * 64 + oo] = fmaxf(s, 0.f);
    }
  }
  __syncthreads();
  if (tid < 16) {
    float s = b2[0];
#pragma unroll
    for (int o = 0; o < 64; ++o) s += z1[tid * 64 + o] * W2[o];
    out[bg * 16 + tid] = rcp_f(1.f + __expf(-s));
  }
}

extern "C" void kernel_launch(void* const* d_in, const int* in_sizes, int n_in,
                              void* d_out, int out_size, void* d_ws, size_t ws_size,
                              hipStream_t stream) {
  (void)in_sizes; (void)n_in; (void)out_size; (void)ws_size;
  const float* seq = (const float*)d_in[0];
  const float* ctx = (const float*)d_in[1];
  const float* tau0 = (const float*)d_in[2];
  const float* Win0 = (const float*)d_in[3];
  const float* Wrec0 = (const float*)d_in[4];
  const float* Wg0 = (const float*)d_in[5];
  const float* bg0 = (const float*)d_in[6];
  const float* tau1 = (const float*)d_in[7];
  const float* Win1 = (const float*)d_in[8];
  const float* Wrec1 = (const float*)d_in[9];
  const float* Wg1 = (const float*)d_in[10];
  const float* bg1 = (const float*)d_in[11];
  const float* W1 = (const float*)d_in[12];
  const float* b1 = (const float*)d_in[13];
  const float* W2 = (const float*)d_in[14];
  const float* b2 = (const float*)d_in[15];
  f16* W = (f16*)d_ws;  // 245760 B of packed fragments

  prep_kernel<<<480, 256, 0, stream>>>(Win0, Wrec0, Wg0, Win1, Wrec1, Wg1, W);
  ltc_kernel<<<32, 512, 0, stream>>>(seq, ctx, tau0, bg0, tau1, bg1, W1, b1, W2,
                                     b2, W, (float*)d_out);
}

// Round 13
// 1666.696 us; speedup vs baseline: 1.6596x; 1.0091x over previous
//
#include <hip/hip_runtime.h>

// LTC RNN (LiquidNeuralNetwork): B=512, S=512, H=128, 2 layers, RK4.
// Round 15: two bit-exact issue/idle cuts on the round-14 base (1628us).
//  - MFMA DIRECT C-IN: peel kc=0 in MM2G/MMIO_B/XPROJ and pass the live
//    C-operand (gx home / zro4 / bgv4) straight into the MFMA src2 field
//    (D and C are separate operands) -> kills ~90 v_mov of accumulator
//    init per wave per step (~5% of VALU issue). Bit-identical.
//  - SLOT REBALANCE: slot A was L0=16 vs L1=32 MFMA; slot B carried L0's
//    +12 XPROJ. Move x-staging to slot D (sq_ld arrives 3 slots after its
//    slot-A issue) and XPROJ to slot A's TAIL so it fills L0's wait for
//    L1's heavier slot A. Per-slot MFMA max-sum 92 -> 80. sq_nxt deleted.
// Kept: lag-1 layer pipeline, 4 slots/step, lgkm-only barriers, u/gx
// ping-pong, pkrtz f16 packing, exp2-fold tanh, even/odd unroll, f16 pack.

typedef _Float16 f16;
typedef __fp16 h16x2 __attribute__((ext_vector_type(2)));  // cvt_pkrtz result
typedef _Float16 f16x4 __attribute__((ext_vector_type(4)));
typedef _Float16 f16x8 __attribute__((ext_vector_type(8)));
typedef float f32x2 __attribute__((ext_vector_type(2)));
typedef float f32x4 __attribute__((ext_vector_type(4)));

#define NSTEP 512
#define OFF_A0 0
#define OFF_A1 32768
#define OFF_AIO 65536
#define OFF_AX 98304
#define W_TOTAL 122880

// LDS byte offsets. hh buffers: [16 cols][136 f16] = 4352 B each.
#define HQ0 0
#define HQ1 4352
#define L0A 8704
#define L0B 13056
#define L1A 17408
#define L1B 21760
#define L1H 26112
#define XT0 30464
#define XT1 32768
#define SMEM_BYTES 35072

__device__ __forceinline__ float rcp_f(float x) { return __builtin_amdgcn_rcpf(x); }

#define FMA2(A, B, C) __builtin_elementwise_fma((A), (B), (C))
#define B2(X) ((f32x2){(X), (X)})
#define ZERO4 ((f32x4){0.f, 0.f, 0.f, 0.f})
#define ZERO2 ((f32x2){0.f, 0.f})

// pack 4 f32 (two f32x2) -> f16x4 via 2x v_cvt_pkrtz_f16_f32
__device__ __forceinline__ f16x4 pk4(f32x2 a, f32x2 b) {
  union { h16x2 h2[2]; f16x4 h4; } u;
  u.h2[0] = __builtin_amdgcn_cvt_pkrtz(a[0], a[1]);
  u.h2[1] = __builtin_amdgcn_cvt_pkrtz(b[0], b[1]);
  return u.h4;
}

// packed tanh: 1 pk_mul + 2 v_exp + 1 pk_add + 2 v_rcp + 1 pk_fma
__device__ __forceinline__ f32x2 tanh2_f(f32x2 z) {
#if __has_builtin(__builtin_amdgcn_exp2f)
  f32x2 zz = z * B2(2.885390081777927f);  // 2*log2(e): exp(2z)=exp2(zz)
  f32x2 e = {__builtin_amdgcn_exp2f(zz[0]), __builtin_amdgcn_exp2f(zz[1])};
#else
  f32x2 zz = z + z;
  f32x2 e = {__expf(zz[0]), __expf(zz[1])};
#endif
  f32x2 d = e + 1.f;
  f32x2 r = {rcp_f(d[0]), rcp_f(d[1])};
  return FMA2(r, B2(-2.f), B2(1.f));
}
// packed sigmoid(t), t in [-1,1]: odd Taylor of 0.5+0.5*tanh(t/2), |err|<3e-6
__device__ __forceinline__ f32x2 sig2_f(f32x2 t) {
  f32x2 s = t * t;
  f32x2 p = FMA2(s, B2(2.1356861e-5f), B2(-2.1081349e-4f));
  p = FMA2(s, p, B2(2.0833333e-3f));
  p = FMA2(s, p, B2(-2.0833333e-2f));
  p = FMA2(s, p, B2(0.25f));
  return FMA2(t, p, B2(0.5f));
}

// lgkm-only barrier: LDS produce->consume needs lgkmcnt(0)+s_barrier only;
// does NOT drain vmcnt (seq prefetch stays in flight across barriers).
#define BAR()                                            \
  do {                                                   \
    asm volatile("s_waitcnt lgkmcnt(0)" ::: "memory");   \
    __builtin_amdgcn_s_barrier();                        \
  } while (0)

// Pack all recurrent-loop weights into f16 MFMA A-fragments.
// A-frag (16x16x32): A[m=lane&15][k=(lane>>4)*8+j], row-tile T = rows 16T..16T+15.
// A0 @0      [T8][sel2][kc4][lane64][j8]  sel0=Wg0 h-part, sel1=Wrec0
// A1 @32768  same                          sel0=Wg1 h-part, sel1=Wrec1
// AIO@65536  same                          sel0=Win1,       sel1=Wg1 x-part
// AX @98304  [T8][sel2][kc3][lane64][j8]  sel0=Win0,       sel1=Wg0 x-part (K=96)
__global__ __launch_bounds__(256) void prep_kernel(
    const float* __restrict__ Win0, const float* __restrict__ Wrec0,
    const float* __restrict__ Wg0, const float* __restrict__ Win1,
    const float* __restrict__ Wrec1, const float* __restrict__ Wg1,
    f16* __restrict__ W) {
  int i = blockIdx.x * 256 + threadIdx.x;
  if (i >= W_TOTAL) return;
  if (i < OFF_AX) {
    int sec = i >> 15;
    int r = i & 32767;
    int j = r & 7, lane = (r >> 3) & 63, kc = (r >> 9) & 3, sel = (r >> 11) & 1,
        w = (r >> 12) & 7;
    int row = w * 16 + (lane & 15);
    int k = kc * 32 + ((lane >> 4) << 3) + j;
    float v;
    if (sec == 0)
      v = sel ? Wrec0[row * 128 + k] : Wg0[row * 224 + 96 + k];
    else if (sec == 1)
      v = sel ? Wrec1[row * 128 + k] : Wg1[row * 256 + 128 + k];
    else
      v = sel ? Wg1[row * 256 + k] : Win1[row * 128 + k];
    W[i] = (f16)v;
  } else {
    int r = i - OFF_AX;
    int j = r & 7, lane = (r >> 3) & 63, g = r >> 9;
    int kc = g % 3, sg = g / 3;
    int sel = sg & 1, w = sg >> 1;
    int row = w * 16 + (lane & 15);
    int k = kc * 32 + ((lane >> 4) << 3) + j;
    W[i] = (f16)(sel ? Wg0[row * 224 + k] : Win0[row * 96 + k]);
  }
}

#define MFMA16(A, B, C) __builtin_amdgcn_mfma_f32_16x16x32_f16((A), (B), (C), 0, 0, 0)

// recurrent matvec, gate-x folded via DIRECT C-in on kc=0 (no acc-init movs):
// ga = G + Wg_h*h ; ra = Wrec*h
#define MM2G(SRC, G)                                                \
  {                                                                 \
    const f16* bp_ = (SRC) + bro;                                   \
    f16x8 bf0_ = *(const f16x8*)(bp_);                              \
    ga[0] = MFMA16(awg[0][0], bf0_, (G)[0]);                        \
    ra[0] = MFMA16(awr[0][0], bf0_, zro4);                          \
    ga[1] = MFMA16(awg[1][0], bf0_, (G)[1]);                        \
    ra[1] = MFMA16(awr[1][0], bf0_, zro4);                          \
    _Pragma("unroll") for (int kc_ = 1; kc_ < 4; ++kc_) {           \
      f16x8 bf_ = *(const f16x8*)(bp_ + kc_ * 32);                  \
      ga[0] = MFMA16(awg[0][kc_], bf_, ga[0]);                      \
      ra[0] = MFMA16(awr[0][kc_], bf_, ra[0]);                      \
      ga[1] = MFMA16(awg[1][kc_], bf_, ga[1]);                      \
      ra[1] = MFMA16(awr[1][kc_], bf_, ra[1]);                      \
    }                                                               \
  }

// L1 io projection, DIRECT C-in: U = Win1*h0; G = bg + Wg1x*h0
#define MMIO_B(SRC, U, G)                                           \
  {                                                                 \
    const f16* bp_ = (SRC) + bro;                                   \
    f16x8 bf0_ = *(const f16x8*)(bp_);                              \
    (U)[0] = MFMA16(au[0][0], bf0_, zro4);                          \
    (G)[0] = MFMA16(ag2[0][0], bf0_, bgv4[0]);                      \
    (U)[1] = MFMA16(au[1][0], bf0_, zro4);                          \
    (G)[1] = MFMA16(ag2[1][0], bf0_, bgv4[1]);                      \
    _Pragma("unroll") for (int kc_ = 1; kc_ < 4; ++kc_) {           \
      f16x8 bf_ = *(const f16x8*)(bp_ + kc_ * 32);                  \
      (U)[0] = MFMA16(au[0][kc_], bf_, (U)[0]);                     \
      (G)[0] = MFMA16(ag2[0][kc_], bf_, (G)[0]);                    \
      (U)[1] = MFMA16(au[1][kc_], bf_, (U)[1]);                     \
      (G)[1] = MFMA16(ag2[1][kc_], bf_, (G)[1]);                    \
    }                                                               \
  }

// L0 x-projection (K=96: 2 chunks from x-tile + ctx), DIRECT C-in:
// U = Win0*x; G = bg + Wg0x*x
#define XPROJ(XSRC, U, G)                                           \
  {                                                                 \
    f16x8 bx0_ = *(const f16x8*)((XSRC) + xro);                     \
    f16x8 bx1_ = *(const f16x8*)((XSRC) + xro + 32);                \
    (U)[0] = MFMA16(au[0][0], bx0_, zro4);                          \
    (G)[0] = MFMA16(ag2[0][0], bx0_, bgv4[0]);                      \
    (U)[1] = MFMA16(au[1][0], bx0_, zro4);                          \
    (G)[1] = MFMA16(ag2[1][0], bx0_, bgv4[1]);                      \
    _Pragma("unroll") for (int i2_ = 0; i2_ < 2; ++i2_) {           \
      (U)[i2_] = MFMA16(au[i2_][1], bx1_, (U)[i2_]);                \
      (G)[i2_] = MFMA16(ag2[i2_][1], bx1_, (G)[i2_]);               \
      (U)[i2_] = MFMA16(au[i2_][2], bctx, (U)[i2_]);                \
      (G)[i2_] = MFMA16(ag2[i2_][2], bctx, (G)[i2_]);               \
    }                                                               \
  }

// RK stage body, packed pairs. Gate arg complete in ga (gx folded via C-in).
// FIRST=1: ksum = kk (stage 1). Else ksum += WC*kk. pkrtz f16 packing.
#define GATEP(WC, HC, DST, FIRST, U)                                \
  _Pragma("unroll") for (int i2_ = 0; i2_ < 2; ++i2_) {             \
    f32x2 hn_[2];                                                   \
    _Pragma("unroll") for (int p_ = 0; p_ < 2; ++p_) {              \
      f32x2 z_ = {ga[i2_][2 * p_], ga[i2_][2 * p_ + 1]};            \
      f32x2 rr_ = {ra[i2_][2 * p_], ra[i2_][2 * p_ + 1]};           \
      f32x2 uu_ = {(U)[i2_][2 * p_], (U)[i2_][2 * p_ + 1]};         \
      f32x2 th_ = tanh2_f(z_);                                      \
      f32x2 gt_ = sig2_f(th_);                                      \
      f32x2 kk_ = FMA2(gt_, rr_,                                    \
                       FMA2(nitv2[i2_][p_], hhc2[i2_][p_], uu_));   \
      ksum2[i2_][p_] = (FIRST) ? kk_ : FMA2(B2(WC), kk_, ksum2[i2_][p_]); \
      f32x2 h_ = FMA2(B2(HC), kk_, hst2[i2_][p_]);                  \
      hhc2[i2_][p_] = h_;                                           \
      hn_[p_] = h_;                                                 \
    }                                                               \
    *(f16x4*)((DST) + jo[i2_]) = pk4(hn_[0], hn_[1]);               \
  }

// RK stage 4: h_new = tanh(h + (ksum+kk)/6) -> state + next stage-1 eval.
#define GATEF(DST, U)                                               \
  _Pragma("unroll") for (int i2_ = 0; i2_ < 2; ++i2_) {             \
    f32x2 hn_[2];                                                   \
    _Pragma("unroll") for (int p_ = 0; p_ < 2; ++p_) {              \
      f32x2 z_ = {ga[i2_][2 * p_], ga[i2_][2 * p_ + 1]};            \
      f32x2 rr_ = {ra[i2_][2 * p_], ra[i2_][2 * p_ + 1]};           \
      f32x2 uu_ = {(U)[i2_][2 * p_], (U)[i2_][2 * p_ + 1]};         \
      f32x2 th_ = tanh2_f(z_);                                      \
      f32x2 gt_ = sig2_f(th_);                                      \
      f32x2 kk_ = FMA2(gt_, rr_,                                    \
                       FMA2(nitv2[i2_][p_], hhc2[i2_][p_], uu_));   \
      f32x2 ks_ = ksum2[i2_][p_] + kk_;                             \
      f32x2 h_ = tanh2_f(FMA2(B2(0.16666667f), ks_, hst2[i2_][p_])); \
      hst2[i2_][p_] = h_;                                           \
      hhc2[i2_][p_] = h_;                                           \
      hn_[p_] = h_;                                                 \
    }                                                               \
    *(f16x4*)((DST) + jo[i2_]) = pk4(hn_[0], hn_[1]);               \
  }

// one full step: 4 slots + 4 barriers. XRD = x(I+1) buffer (read by XPROJ at
// slot-A tail), XWR = buffer for x(I+2) (staged in slot D from sq_ld).
// UC/GC = this step's u/gx home, UN/GN = next step's (ping-pong).
#define STEP(I, HPREV, XRD, XWR, HDST, UC, GC, UN, GN, L0ON, L1ON)        \
  {                                                                       \
    if (isL0) {                                                           \
      if (L0ON) {                                                         \
        if (tid < 256 && (I) + 2 < NSTEP)                                 \
          sq_ld = *(const float4*)(seq + seqrow + (size_t)((I) + 2) * 64);\
        MM2G(HPREV, GC);                                                  \
        GATEP(1.0f, 0.5f, bufA, 1, UC);                                   \
        if ((I) + 1 < NSTEP) { XPROJ(XRD, UN, GN); }                      \
      }                                                                   \
    } else if (L1ON) {                                                    \
      MMIO_B(HPREV, UC, GC);                                              \
      MM2G(l1h, GC);                                                      \
      GATEP(1.0f, 0.5f, bufA, 1, UC);                                     \
    }                                                                     \
    BAR();                                                                \
    if ((isL0 && (L0ON)) || (!isL0 && (L1ON))) {                          \
      MM2G(bufA, GC);                                                     \
      GATEP(2.0f, 0.5f, bufB, 0, UC);                                     \
    }                                                                     \
    BAR();                                                                \
    if ((isL0 && (L0ON)) || (!isL0 && (L1ON))) {                          \
      MM2G(bufB, GC);                                                     \
      GATEP(2.0f, 1.0f, bufA, 0, UC);                                     \
    }                                                                     \
    BAR();                                                                \
    if (isL0) {                                                           \
      if (L0ON) {                                                         \
        MM2G(bufA, GC);                                                   \
        GATEF(HDST, UC);                                                  \
        if (tid < 256 && (I) + 2 < NSTEP) {                               \
          f32x2 sa_ = {sq_ld.x, sq_ld.y};                                 \
          f32x2 sb_ = {sq_ld.z, sq_ld.w};                                 \
          *(f16x4*)((XWR) + xoff) = pk4(sa_, sb_);                        \
        }                                                                 \
      }                                                                   \
    } else if (L1ON) {                                                    \
      MM2G(bufA, GC);                                                     \
      GATEF(l1h, UC);                                                     \
    }                                                                     \
    BAR();                                                                \
  }

__global__ __launch_bounds__(512, 1) void ltc_kernel(
    const float* __restrict__ seq, const float* __restrict__ ctx,
    const float* __restrict__ tau0p, const float* __restrict__ bg0p,
    const float* __restrict__ tau1p, const float* __restrict__ bg1p,
    const float* __restrict__ W1, const float* __restrict__ b1,
    const float* __restrict__ W2, const float* __restrict__ b2,
    const f16* __restrict__ W, float* __restrict__ out) {
  __shared__ __align__(16) char smem[SMEM_BYTES];
  f16* hq0 = (f16*)(smem + HQ0);
  f16* hq1 = (f16*)(smem + HQ1);
  f16* l0a = (f16*)(smem + L0A);
  f16* l0b = (f16*)(smem + L0B);
  f16* l1a = (f16*)(smem + L1A);
  f16* l1b = (f16*)(smem + L1B);
  f16* l1h = (f16*)(smem + L1H);
  f16* xt0 = (f16*)(smem + XT0);
  f16* xt1 = (f16*)(smem + XT1);

  const int tid = threadIdx.x;
  const int w8 = tid >> 6, lane = tid & 63;
  const int q = lane >> 4, c = lane & 15;
  const int wl = w8 & 3;
  const bool isL0 = (w8 < 4);
  const int bg = blockIdx.x;
  int jb[2];
  jb[0] = 32 * wl + 4 * q;
  jb[1] = jb[0] + 16;
  // hoisted LDS offsets (loop-invariant)
  const int bro = c * 136 + 8 * q;   // B-frag read offset in hh buffers
  const int xro = c * 72 + 8 * q;    // x-tile read offset
  int jo[2];
  jo[0] = c * 136 + jb[0];           // gate write offsets
  jo[1] = c * 136 + jb[1];
  const int bs = tid >> 4, fp = tid & 15;
  const int xoff = bs * 72 + 4 * fp; // x-tile stage offset

  f16* bufA = isL0 ? l0a : l1a;
  f16* bufB = isL0 ? l0b : l1b;

  // persistent zero C-operand for MFMA direct C-in
  const f32x4 zro4 = ZERO4;

  // ---- weight fragments -> VGPRs (held for whole kernel) ----
  f16x8 awg[2][4], awr[2][4], au[2][4], ag2[2][4];
  f16x8 bctx;
  if (isL0) {
#pragma unroll
    for (int i2 = 0; i2 < 2; ++i2) {
      int T = 2 * wl + i2;
#pragma unroll
      for (int kc = 0; kc < 4; ++kc) {
        awg[i2][kc] = *(const f16x8*)(W + OFF_A0 + (((T * 2 + 0) * 4 + kc) * 64 + lane) * 8);
        awr[i2][kc] = *(const f16x8*)(W + OFF_A0 + (((T * 2 + 1) * 4 + kc) * 64 + lane) * 8);
      }
#pragma unroll
      for (int kc = 0; kc < 3; ++kc) {
        au[i2][kc] = *(const f16x8*)(W + OFF_AX + (((T * 2 + 0) * 3 + kc) * 64 + lane) * 8);
        ag2[i2][kc] = *(const f16x8*)(W + OFF_AX + (((T * 2 + 1) * 3 + kc) * 64 + lane) * 8);
      }
      au[i2][3] = (f16x8)(f16)0.f;
      ag2[i2][3] = (f16x8)(f16)0.f;
    }
    const float* cp = ctx + (bg * 16 + c) * 32 + 8 * q;
#pragma unroll
    for (int j = 0; j < 8; ++j) bctx[j] = (f16)cp[j];
  } else {
#pragma unroll
    for (int i2 = 0; i2 < 2; ++i2) {
      int T = 2 * wl + i2;
#pragma unroll
      for (int kc = 0; kc < 4; ++kc) {
        awg[i2][kc] = *(const f16x8*)(W + OFF_A1 + (((T * 2 + 0) * 4 + kc) * 64 + lane) * 8);
        awr[i2][kc] = *(const f16x8*)(W + OFF_A1 + (((T * 2 + 1) * 4 + kc) * 64 + lane) * 8);
        au[i2][kc] = *(const f16x8*)(W + OFF_AIO + (((T * 2 + 0) * 4 + kc) * 64 + lane) * 8);
        ag2[i2][kc] = *(const f16x8*)(W + OFF_AIO + (((T * 2 + 1) * 4 + kc) * 64 + lane) * 8);
      }
    }
  }

  // per-lane params for the 8 owned rows (packed pairs, itv negated)
  const float* taup = isL0 ? tau0p : tau1p;
  const float* bgp = isL0 ? bg0p : bg1p;
  f32x2 nitv2[2][2];
  f32x4 bgv4[2];
#pragma unroll
  for (int i2 = 0; i2 < 2; ++i2)
#pragma unroll
    for (int r = 0; r < 4; ++r) {
      float t = taup[jb[i2] + r];
      nitv2[i2][r >> 1][r & 1] = -1.f / (logf(1.f + __expf(t)) + 1.f);
      bgv4[i2][r] = bgp[jb[i2] + r];
    }

  f32x2 hst2[2][2], hhc2[2][2], ksum2[2][2];
  f32x4 ga[2], ra[2], u4a[2], gx4a[2], u4b[2], gx4b[2];
#pragma unroll
  for (int i2 = 0; i2 < 2; ++i2) {
#pragma unroll
    for (int p = 0; p < 2; ++p) {
      hst2[i2][p] = ZERO2;
      hhc2[i2][p] = ZERO2;
      ksum2[i2][p] = ZERO2;
    }
    u4a[i2] = ZERO4; gx4a[i2] = ZERO4;
    u4b[i2] = ZERO4; gx4b[i2] = ZERO4;
  }

  // zero initial-state buffers: hq1 (h0 at t=-1) and l1h (h1 at t=-1)
  for (int j = tid; j < 2176; j += 512) {
    hq1[j] = (f16)0.f;
    l1h[j] = (f16)0.f;
  }
  // pre-stage x(0) AND x(1): 256 L0 threads, float4 each
  const size_t seqrow = ((size_t)(bg * 16 + bs)) * NSTEP * 64 + 4 * fp;
  float4 sq_ld = {0.f, 0.f, 0.f, 0.f};
  if (tid < 256) {
    float4 s0 = *(const float4*)(seq + seqrow);
    f32x2 a0 = {s0.x, s0.y}, b0 = {s0.z, s0.w};
    *(f16x4*)(xt0 + xoff) = pk4(a0, b0);
    float4 s1 = *(const float4*)(seq + seqrow + 64);
    f32x2 a1 = {s1.x, s1.y}, b1v = {s1.z, s1.w};
    *(f16x4*)(xt1 + xoff) = pk4(a1, b1v);
  }
  __syncthreads();
  // u/gx for step 0 directly into the even-step home (pipeline warm-up)
  if (isL0) { XPROJ(xt0, u4a, gx4a); }

  // i=0 (even: hprev=hq1, XRD=xt1 (x1), XWR=xt0 (x2), hdst=hq0; UC=a), L1 idle
  STEP(0, hq1, xt1, xt0, hq0, u4a, gx4a, u4b, gx4b, true, false);
  // pairs (odd, even): odd steps UC=b / stage into xt1; even steps UC=a / xt0.
#pragma unroll 1
  for (int i = 1; i < NSTEP; i += 2) {
    STEP(i, hq0, xt0, xt1, hq1, u4b, gx4b, u4a, gx4a, true, true);
    STEP(i + 1, hq1, xt1, xt0, hq0, u4a, gx4a, u4b, gx4b, (i + 1) < NSTEP, true);
  }

  // ======================= classifier epilogue ===========================
  float* h1f = (float*)smem;  // [16][132] f32
  if (!isL0) {
#pragma unroll
    for (int i2 = 0; i2 < 2; ++i2)
#pragma unroll
      for (int p = 0; p < 2; ++p)
        *(f32x2*)(h1f + c * 132 + jb[i2] + 2 * p) = hst2[i2][p];
  }
  __syncthreads();
  float* z1 = (float*)(smem + 16 * 132 * 4);  // [16][64] f32
  {
    int b = tid >> 5, o = tid & 31;
#pragma unroll
    for (int hlf = 0; hlf < 2; ++hlf) {
      int oo = o + 32 * hlf;
      const float* wr = W1 + oo * 128;
      const float* hr = h1f + b * 132;
      float s = 0.f;
#pragma unroll
      for (int j = 0; j < 128; j += 4) {
        f32x4 wv = *(const f32x4*)(wr + j);
        f32x4 hv = *(const f32x4*)(hr + j);
        s += wv[0] * hv[0] + wv[1] * hv[1] + wv[2] * hv[2] + wv[3] * hv[3];
      }
      s += b1[oo];
      z1[b * 64 + oo] = fmaxf(s, 0.f);
    }
  }
  __syncthreads();
  if (tid < 16) {
    float s = b2[0];
#pragma unroll
    for (int o = 0; o < 64; ++o) s += z1[tid * 64 + o] * W2[o];
    out[bg * 16 + tid] = rcp_f(1.f + __expf(-s));
  }
}

extern "C" void kernel_launch(void* const* d_in, const int* in_sizes, int n_in,
                              void* d_out, int out_size, void* d_ws, size_t ws_size,
                              hipStream_t stream) {
  (void)in_sizes; (void)n_in; (void)out_size; (void)ws_size;
  const float* seq = (const float*)d_in[0];
  const float* ctx = (const float*)d_in[1];
  const float* tau0 = (const float*)d_in[2];
  const float* Win0 = (const float*)d_in[3];
  const float* Wrec0 = (const float*)d_in[4];
  const float* Wg0 = (const float*)d_in[5];
  const float* bg0 = (const float*)d_in[6];
  const float* tau1 = (const float*)d_in[7];
  const float* Win1 = (const float*)d_in[8];
  const float* Wrec1 = (const float*)d_in[9];
  const float* Wg1 = (const float*)d_in[10];
  const float* bg1 = (const float*)d_in[11];
  const float* W1 = (const float*)d_in[12];
  const float* b1 = (const float*)d_in[13];
  const float* W2 = (const float*)d_in[14];
  const float* b2 = (const float*)d_in[15];
  f16* W = (f16*)d_ws;  // 245760 B of packed fragments

  prep_kernel<<<480, 256, 0, stream>>>(Win0, Wrec0, Wg0, Win1, Wrec1, Wg1, W);
  ltc_kernel<<<32, 512, 0, stream>>>(seq, ctx, tau0, bg0, tau1, bg1, W1, b1, W2,
                                     b2, W, (float*)d_out);
}